// Round 1
// baseline (323.202 us; speedup 1.0000x reference)
//
#include <hip/hip_runtime.h>
#include <math.h>

#define D_MODEL 1024
#define T_SEQ   2048
#define BATCH   2
#define NH      16
#define HD      64

typedef __attribute__((ext_vector_type(8))) short bf16x8;
typedef __attribute__((ext_vector_type(4))) float f32x4;

__device__ inline unsigned short f2bf(float f) {
  union { float f; unsigned int u; } v; v.f = f;
  unsigned int u = v.u;
  unsigned int r = u + 0x7fffu + ((u >> 16) & 1u);
  return (unsigned short)(r >> 16);
}
__device__ inline float bf2f(unsigned short s) {
  union { unsigned int u; float f; } v; v.u = ((unsigned int)s) << 16;
  return v.f;
}

// ---------------- cast fp32 -> bf16, vectorized ----------------
__global__ void cast_kernel(const float* __restrict__ in, unsigned short* __restrict__ out, int n4) {
  int id = blockIdx.x * blockDim.x + threadIdx.x;
  if (id >= n4) return;
  float4 v = ((const float4*)in)[id];
  ushort4 o;
  o.x = f2bf(v.x); o.y = f2bf(v.y); o.z = f2bf(v.z); o.w = f2bf(v.w);
  ((ushort4*)out)[id] = o;
}

// ---------------- GEMM: C[M,N] = A[M,K] * B[N,K]^T  (bf16 in, fp32 acc) ----------------
// 128x128 tile, BK=32, 4 waves (2x2), each wave 64x64 via 4x4 16x16x32 MFMA frags.
template<bool F32OUT>
__global__ __launch_bounds__(256)
void gemm_bt(const unsigned short* __restrict__ A, const unsigned short* __restrict__ B,
             void* __restrict__ Cout, int M, int N, int K) {
  __shared__ __align__(16) unsigned short As[128][40];  // +8 pad, 80B row stride (16B multiple)
  __shared__ __align__(16) unsigned short Bs[128][40];
  const int tid  = threadIdx.x;
  const int lane = tid & 63;
  const int wid  = tid >> 6;
  const int wr   = wid >> 1, wc = wid & 1;
  const int bm   = blockIdx.y * 128;
  const int bn   = blockIdx.x * 128;

  f32x4 acc[4][4];
#pragma unroll
  for (int i = 0; i < 4; i++)
#pragma unroll
    for (int j = 0; j < 4; j++) acc[i][j] = (f32x4){0.f, 0.f, 0.f, 0.f};

  const int r0 = tid >> 2;          // 0..63
  const int c0 = (tid & 3) * 8;     // 0,8,16,24
  const int fr = lane & 15;
  const int fk = (lane >> 4) * 8;

  for (int kb = 0; kb < K; kb += 32) {
    *(bf16x8*)&As[r0     ][c0] = *(const bf16x8*)(A + (size_t)(bm + r0     ) * K + kb + c0);
    *(bf16x8*)&As[r0 + 64][c0] = *(const bf16x8*)(A + (size_t)(bm + r0 + 64) * K + kb + c0);
    *(bf16x8*)&Bs[r0     ][c0] = *(const bf16x8*)(B + (size_t)(bn + r0     ) * K + kb + c0);
    *(bf16x8*)&Bs[r0 + 64][c0] = *(const bf16x8*)(B + (size_t)(bn + r0 + 64) * K + kb + c0);
    __syncthreads();
    bf16x8 a[4], b[4];
#pragma unroll
    for (int mi = 0; mi < 4; mi++) a[mi] = *(const bf16x8*)&As[wr * 64 + mi * 16 + fr][fk];
#pragma unroll
    for (int ni = 0; ni < 4; ni++) b[ni] = *(const bf16x8*)&Bs[wc * 64 + ni * 16 + fr][fk];
#pragma unroll
    for (int mi = 0; mi < 4; mi++)
#pragma unroll
      for (int ni = 0; ni < 4; ni++)
        acc[mi][ni] = __builtin_amdgcn_mfma_f32_16x16x32_bf16(a[mi], b[ni], acc[mi][ni], 0, 0, 0);
    __syncthreads();
  }

  const int fc = lane & 15, fq = lane >> 4;
#pragma unroll
  for (int mi = 0; mi < 4; mi++)
#pragma unroll
    for (int ni = 0; ni < 4; ni++) {
      int col = bn + wc * 64 + ni * 16 + fc;
#pragma unroll
      for (int r = 0; r < 4; r++) {
        int row = bm + wr * 64 + mi * 16 + fq * 4 + r;
        if (F32OUT) ((float*)Cout)[(size_t)row * N + col] = acc[mi][ni][r];
        else ((unsigned short*)Cout)[(size_t)row * N + col] = f2bf(acc[mi][ni][r]);
      }
    }
}

// ---------------- RoPE in-place on bf16 (b,t,o) for Q and K ----------------
__global__ void rope_kernel(unsigned short* __restrict__ Qp, unsigned short* __restrict__ Kp,
                            const int* __restrict__ pos, int total) {
  int id = blockIdx.x * blockDim.x + threadIdx.x;
  if (id >= total) return;
  int m  = id >> 9;        // row in [0, B*T)
  int p2 = id & 511;       // pair index within row; even col = 2*p2
  int p  = p2 & 31;        // pair index within head
  float posf = (float)pos[m];
  float inv  = powf(10000.0f, (float)(-2 * p) / 64.0f);
  float ang  = posf * inv;
  float sn, cs;
  sincosf(ang, &sn, &cs);
  size_t off = (size_t)m * D_MODEL + 2 * p2;
  float q1 = bf2f(Qp[off]), q2 = bf2f(Qp[off + 1]);
  Qp[off]     = f2bf(q1 * cs - q2 * sn);
  Qp[off + 1] = f2bf(q1 * sn + q2 * cs);
  float k1 = bf2f(Kp[off]), k2 = bf2f(Kp[off + 1]);
  Kp[off]     = f2bf(k1 * cs - k2 * sn);
  Kp[off + 1] = f2bf(k1 * sn + k2 * cs);
}

// ---------------- Flash attention, causal, bf16 MFMA ----------------
// grid: (T/64, B*H). 4 waves/block; wave w owns q rows [qt*64+w*16, +16).
__global__ __launch_bounds__(256)
void attn_kernel(const unsigned short* __restrict__ Q, const unsigned short* __restrict__ K,
                 const unsigned short* __restrict__ V, unsigned short* __restrict__ O) {
  __shared__ __align__(16) unsigned short Vs[64][72];      // 64x64 + pad, 144B stride
  __shared__ __align__(16) unsigned short Ps[4][16][72];   // per-wave P (16x64) + pad

  const int bh = blockIdx.y;
  const int b  = bh >> 4, h = bh & 15;
  const int qt = blockIdx.x;
  const int tid = threadIdx.x, lane = tid & 63, wid = tid >> 6;

  const size_t base = ((size_t)b * T_SEQ) * D_MODEL + h * HD;
  const unsigned short* Qb = Q + base;
  const unsigned short* Kb = K + base;
  const unsigned short* Vb = V + base;

  const int fr = lane & 15;        // A-row / B-col / C-col index
  const int fg = lane >> 4;        // quarter-wave group
  const int qrow0 = qt * 64 + wid * 16;

  bf16x8 qf[2];
  {
    const unsigned short* qp = Qb + (size_t)(qrow0 + fr) * D_MODEL + fg * 8;
    qf[0] = *(const bf16x8*)qp;
    qf[1] = *(const bf16x8*)(qp + 32);
  }

  float m_run[4], l_run[4];
  f32x4 acc[4];
#pragma unroll
  for (int r = 0; r < 4; r++) { m_run[r] = -INFINITY; l_run[r] = 0.f; }
#pragma unroll
  for (int d = 0; d < 4; d++) acc[d] = (f32x4){0.f, 0.f, 0.f, 0.f};

  const int vr0 = tid >> 3, vc0 = (tid & 7) * 8;
  const int ntiles = qt + 1;

  for (int kt = 0; kt < ntiles; ++kt) {
    const int kvb = kt * 64;
    // stage V tile (64x64) cooperatively
    *(bf16x8*)&Vs[vr0     ][vc0] = *(const bf16x8*)(Vb + (size_t)(kvb + vr0     ) * D_MODEL + vc0);
    *(bf16x8*)&Vs[vr0 + 32][vc0] = *(const bf16x8*)(Vb + (size_t)(kvb + vr0 + 32) * D_MODEL + vc0);

    // S = Q K^T / 8 for this wave's 16 rows x 64 kv cols
    float s[4][4];
#pragma unroll
    for (int nt = 0; nt < 4; ++nt) {
      const unsigned short* kp = Kb + (size_t)(kvb + nt * 16 + fr) * D_MODEL + fg * 8;
      bf16x8 kf0 = *(const bf16x8*)kp;
      bf16x8 kf1 = *(const bf16x8*)(kp + 32);
      f32x4 sa = (f32x4){0.f, 0.f, 0.f, 0.f};
      sa = __builtin_amdgcn_mfma_f32_16x16x32_bf16(qf[0], kf0, sa, 0, 0, 0);
      sa = __builtin_amdgcn_mfma_f32_16x16x32_bf16(qf[1], kf1, sa, 0, 0, 0);
#pragma unroll
      for (int r = 0; r < 4; r++) s[nt][r] = sa[r] * 0.125f;
    }
    if (kt == qt) {  // diagonal tile: causal mask
#pragma unroll
      for (int nt = 0; nt < 4; ++nt) {
        int col = kvb + nt * 16 + fr;
#pragma unroll
        for (int r = 0; r < 4; r++) {
          int row = qrow0 + fg * 4 + r;
          if (col > row) s[nt][r] = -INFINITY;
        }
      }
    }
    // online softmax (row r of lane = qrow0 + fg*4 + r; 16 cols spread over 16 lanes)
    float tm[4];
#pragma unroll
    for (int r = 0; r < 4; r++) tm[r] = fmaxf(fmaxf(s[0][r], s[1][r]), fmaxf(s[2][r], s[3][r]));
#pragma unroll
    for (int off = 1; off < 16; off <<= 1)
#pragma unroll
      for (int r = 0; r < 4; r++) tm[r] = fmaxf(tm[r], __shfl_xor(tm[r], off));

    float scale[4], rs[4];
#pragma unroll
    for (int r = 0; r < 4; r++) {
      float mn = fmaxf(m_run[r], tm[r]);
      scale[r] = expf(m_run[r] - mn);
      m_run[r] = mn;
      rs[r] = 0.f;
    }
    float pr[4][4];
#pragma unroll
    for (int nt = 0; nt < 4; nt++)
#pragma unroll
      for (int r = 0; r < 4; r++) { float p = expf(s[nt][r] - m_run[r]); pr[nt][r] = p; rs[r] += p; }
#pragma unroll
    for (int off = 1; off < 16; off <<= 1)
#pragma unroll
      for (int r = 0; r < 4; r++) rs[r] += __shfl_xor(rs[r], off);
#pragma unroll
    for (int r = 0; r < 4; r++) l_run[r] = l_run[r] * scale[r] + rs[r];
#pragma unroll
    for (int d = 0; d < 4; d++)
#pragma unroll
      for (int r = 0; r < 4; r++) acc[d][r] *= scale[r];

    // P -> LDS (C layout -> A layout transpose through LDS)
#pragma unroll
    for (int nt = 0; nt < 4; nt++)
#pragma unroll
      for (int r = 0; r < 4; r++)
        Ps[wid][fg * 4 + r][nt * 16 + fr] = f2bf(pr[nt][r]);
    __syncthreads();   // V staged + P written

    // PV: acc += P(16x64) * V(64x64)
    bf16x8 pa[2];
    pa[0] = *(const bf16x8*)&Ps[wid][fr][fg * 8];
    pa[1] = *(const bf16x8*)&Ps[wid][fr][32 + fg * 8];
#pragma unroll
    for (int d = 0; d < 4; ++d) {
#pragma unroll
      for (int ks = 0; ks < 2; ++ks) {
        bf16x8 vb;
#pragma unroll
        for (int j = 0; j < 8; j++) vb[j] = (short)Vs[ks * 32 + fg * 8 + j][d * 16 + fr];
        acc[d] = __builtin_amdgcn_mfma_f32_16x16x32_bf16(pa[ks], vb, acc[d], 0, 0, 0);
      }
    }
    __syncthreads();   // protect Vs/Ps before next iteration overwrites
  }

  // epilogue: O row-major (b, t, h*64+d)
#pragma unroll
  for (int d = 0; d < 4; ++d)
#pragma unroll
    for (int r = 0; r < 4; r++) {
      int row = qrow0 + fg * 4 + r;
      float o = acc[d][r] / l_run[r];
      O[((size_t)b * T_SEQ + row) * D_MODEL + h * HD + d * 16 + fr] = f2bf(o);
    }
}

// ---------------- launch ----------------
extern "C" void kernel_launch(void* const* d_in, const int* in_sizes, int n_in,
                              void* d_out, int out_size, void* d_ws, size_t ws_size,
                              hipStream_t stream) {
  const float* x  = (const float*)d_in[0];
  const int*   pos = (const int*)d_in[1];
  const float* Wq = (const float*)d_in[2];
  const float* Wk = (const float*)d_in[3];
  const float* Wv = (const float*)d_in[4];
  const float* Wo = (const float*)d_in[5];

  const size_t M = (size_t)BATCH * T_SEQ;     // 4096
  const size_t DD = (size_t)D_MODEL * D_MODEL;

  char* ws = (char*)d_ws;
  unsigned short* xb  = (unsigned short*)ws; ws += M * D_MODEL * 2;
  unsigned short* Wqb = (unsigned short*)ws; ws += DD * 2;
  unsigned short* Wkb = (unsigned short*)ws; ws += DD * 2;
  unsigned short* Wvb = (unsigned short*)ws; ws += DD * 2;
  unsigned short* Wob = (unsigned short*)ws; ws += DD * 2;
  unsigned short* Qp  = (unsigned short*)ws; ws += M * D_MODEL * 2;
  unsigned short* Kp  = (unsigned short*)ws; ws += M * D_MODEL * 2;
  unsigned short* Vp  = (unsigned short*)ws; ws += M * D_MODEL * 2;
  unsigned short* Ob  = (unsigned short*)ws; ws += M * D_MODEL * 2;

  // casts
  int n4x = (int)(M * D_MODEL / 4);
  cast_kernel<<<(n4x + 255) / 256, 256, 0, stream>>>(x, xb, n4x);
  int n4w = (int)(DD / 4);
  cast_kernel<<<(n4w + 255) / 256, 256, 0, stream>>>(Wq, Wqb, n4w);
  cast_kernel<<<(n4w + 255) / 256, 256, 0, stream>>>(Wk, Wkb, n4w);
  cast_kernel<<<(n4w + 255) / 256, 256, 0, stream>>>(Wv, Wvb, n4w);
  cast_kernel<<<(n4w + 255) / 256, 256, 0, stream>>>(Wo, Wob, n4w);

  // projections
  dim3 ggrid(D_MODEL / 128, (unsigned)(M / 128));
  gemm_bt<false><<<ggrid, 256, 0, stream>>>(xb, Wqb, Qp, (int)M, D_MODEL, D_MODEL);
  gemm_bt<false><<<ggrid, 256, 0, stream>>>(xb, Wkb, Kp, (int)M, D_MODEL, D_MODEL);
  gemm_bt<false><<<ggrid, 256, 0, stream>>>(xb, Wvb, Vp, (int)M, D_MODEL, D_MODEL);

  // rope on Q,K in place
  int total = (int)(M * 512);
  rope_kernel<<<(total + 255) / 256, 256, 0, stream>>>(Qp, Kp, pos, total);

  // attention
  dim3 agrid(T_SEQ / 64, BATCH * NH);
  attn_kernel<<<agrid, 256, 0, stream>>>(Qp, Kp, Vp, Ob);

  // output projection (fp32 out)
  gemm_bt<true><<<ggrid, 256, 0, stream>>>(Ob, Wob, d_out, (int)M, D_MODEL, D_MODEL);
}

// Round 3
// 229.115 us; speedup vs baseline: 1.4107x; 1.4107x over previous
//
#include <hip/hip_runtime.h>
#include <math.h>
#include <stdint.h>

#define D_MODEL 1024
#define T_SEQ   2048
#define BATCH   2
#define NH      16
#define HD      64

typedef __attribute__((ext_vector_type(8))) short bf16x8;
typedef __attribute__((ext_vector_type(4))) float f32x4;

__device__ inline unsigned short f2bf(float f) {
  union { float f; unsigned int u; } v; v.f = f;
  unsigned int u = v.u;
  unsigned int r = u + 0x7fffu + ((u >> 16) & 1u);
  return (unsigned short)(r >> 16);
}
__device__ inline float bf2f(unsigned short s) {
  union { unsigned int u; float f; } v; v.u = ((unsigned int)s) << 16;
  return v.f;
}

// async global->LDS, 16B per lane, LDS dest = wave-uniform base + lane*16
#define GLDS16(g, l) __builtin_amdgcn_global_load_lds( \
  reinterpret_cast<const __attribute__((address_space(1))) void*>(reinterpret_cast<uintptr_t>(g)), \
  reinterpret_cast<__attribute__((address_space(3))) void*>(reinterpret_cast<uintptr_t>(l)), 16, 0, 0)

// ---------------- casts fp32 -> bf16 ----------------
__global__ void cast_kernel(const float* __restrict__ in, unsigned short* __restrict__ out, int n4) {
  int id = blockIdx.x * blockDim.x + threadIdx.x;
  if (id >= n4) return;
  float4 v = ((const float4*)in)[id];
  ushort4 o;
  o.x = f2bf(v.x); o.y = f2bf(v.y); o.z = f2bf(v.z); o.w = f2bf(v.w);
  ((ushort4*)out)[id] = o;
}

__global__ void cast4_kernel(const float* __restrict__ s0, const float* __restrict__ s1,
                             const float* __restrict__ s2, const float* __restrict__ s3,
                             unsigned short* __restrict__ d0, unsigned short* __restrict__ d1,
                             unsigned short* __restrict__ d2, unsigned short* __restrict__ d3) {
  int id = blockIdx.x * blockDim.x + threadIdx.x;   // 4 * 2^18
  int m = id >> 18, r = id & ((1 << 18) - 1);
  const float* s = (m == 0) ? s0 : (m == 1) ? s1 : (m == 2) ? s2 : s3;
  unsigned short* dd = (m == 0) ? d0 : (m == 1) ? d1 : (m == 2) ? d2 : d3;
  float4 v = ((const float4*)s)[r];
  ushort4 o;
  o.x = f2bf(v.x); o.y = f2bf(v.y); o.z = f2bf(v.z); o.w = f2bf(v.w);
  ((ushort4*)dd)[r] = o;
}

// ---------------- GEMM: C[M,1024] = A[M,K] * B[1024,K]^T (bf16, fp32 acc) ----------------
// m97 structure: 128xBN tile, BK=32, linear LDS, global_load_lds width 16.
// 3 matrices fused along grid.x (B/C selected per block).
template<int BN, bool F32OUT>
__global__ __launch_bounds__(256)
void gemm_bt(const unsigned short* __restrict__ A,
             const unsigned short* __restrict__ B0, const unsigned short* __restrict__ B1,
             const unsigned short* __restrict__ B2,
             void* __restrict__ C0, void* __restrict__ C1, void* __restrict__ C2,
             int M, int K) {
  constexpr int NPM = 1024 / BN;   // N-blocks per matrix
  constexpr int NWC = BN / 64;     // wave columns
  constexpr int MI  = 2 * NWC;     // M-frags per wave
  __shared__ __align__(16) unsigned short As[128 * 32];
  __shared__ __align__(16) unsigned short Bs[BN * 32];

  const int tid = threadIdx.x, lane = tid & 63, wid = tid >> 6;
  const int wr = wid / NWC, wc = wid % NWC;
  const int bx = blockIdx.x;
  const int mat = bx / NPM;
  const int bn = (bx % NPM) * BN;
  const int bm = blockIdx.y * 128;
  const unsigned short* B = (mat == 0) ? B0 : (mat == 1) ? B1 : B2;
  void* C = (mat == 0) ? C0 : (mat == 1) ? C1 : C2;

  f32x4 acc[MI][4];
#pragma unroll
  for (int i = 0; i < MI; i++)
#pragma unroll
    for (int j = 0; j < 4; j++) acc[i][j] = (f32x4){0.f, 0.f, 0.f, 0.f};

  const int fr = lane & 15, fg = lane >> 4;
  const int lrow = lane >> 2, lcol = (lane & 3) * 8;

  for (int kb = 0; kb < K; kb += 32) {
    // stage A (128x32): each wave covers 32 rows via 2 calls of 16 rows
#pragma unroll
    for (int c = 0; c < 2; ++c) {
      int rb = wid * 32 + c * 16;
      GLDS16(A + (size_t)(bm + rb + lrow) * K + kb + lcol, As + rb * 32);
    }
    // stage B (BNx32)
#pragma unroll
    for (int c = 0; c < BN / 64; ++c) {
      int rb = wid * (BN / 4) + c * 16;
      GLDS16(B + (size_t)(bn + rb + lrow) * K + kb + lcol, Bs + rb * 32);
    }
    __syncthreads();
    bf16x8 a[MI], bq[4];
#pragma unroll
    for (int mi = 0; mi < MI; mi++)
      a[mi] = *(const bf16x8*)&As[(wr * (16 * MI) + mi * 16 + fr) * 32 + fg * 8];
#pragma unroll
    for (int ni = 0; ni < 4; ni++)
      bq[ni] = *(const bf16x8*)&Bs[(wc * 64 + ni * 16 + fr) * 32 + fg * 8];
#pragma unroll
    for (int mi = 0; mi < MI; mi++)
#pragma unroll
      for (int ni = 0; ni < 4; ni++)
        acc[mi][ni] = __builtin_amdgcn_mfma_f32_16x16x32_bf16(a[mi], bq[ni], acc[mi][ni], 0, 0, 0);
    __syncthreads();
  }

  const int fc = lane & 15, fq = lane >> 4;
#pragma unroll
  for (int mi = 0; mi < MI; mi++)
#pragma unroll
    for (int ni = 0; ni < 4; ni++) {
      int col = bn + wc * 64 + ni * 16 + fc;
#pragma unroll
      for (int r = 0; r < 4; r++) {
        int row = bm + wr * (16 * MI) + mi * 16 + fq * 4 + r;
        if (F32OUT) ((float*)C)[(size_t)row * 1024 + col] = acc[mi][ni][r];
        else ((unsigned short*)C)[(size_t)row * 1024 + col] = f2bf(acc[mi][ni][r]);
      }
    }
}

// ---------------- RoPE in-place on bf16 (b,t,o) for Q and K ----------------
__global__ void rope_kernel(unsigned short* __restrict__ Qp, unsigned short* __restrict__ Kp,
                            const int* __restrict__ pos, int total) {
  int id = blockIdx.x * blockDim.x + threadIdx.x;
  if (id >= total) return;
  int m  = id >> 9;
  int p2 = id & 511;
  int p  = p2 & 31;
  float posf = (float)pos[m];
  float inv  = powf(10000.0f, (float)(-2 * p) / 64.0f);
  float ang  = posf * inv;
  float sn, cs;
  sincosf(ang, &sn, &cs);
  size_t off = (size_t)m * D_MODEL + 2 * p2;
  float q1 = bf2f(Qp[off]), q2 = bf2f(Qp[off + 1]);
  Qp[off]     = f2bf(q1 * cs - q2 * sn);
  Qp[off + 1] = f2bf(q1 * sn + q2 * cs);
  float k1 = bf2f(Kp[off]), k2 = bf2f(Kp[off + 1]);
  Kp[off]     = f2bf(k1 * cs - k2 * sn);
  Kp[off + 1] = f2bf(k1 * sn + k2 * cs);
}

// ---------------- Flash attention, causal, bf16 MFMA ----------------
// Round-1-verified structure (S = Q K^T, C layout col=fr,row=fg*4+r; P via
// per-wave LDS). New: V stored TRANSPOSED in LDS (Vt[d][kv], 128B rows,
// XOR-swizzle byte^=((d&7)<<4)) -> PV B-frags are 8 aligned ds_read_b128
// instead of 64 scalar ds_read_u16 (the round-1 9.2M bank conflicts).
// Double-buffered Vt: one barrier per tile; next-tile V global loads issued
// before compute (latency hidden under QK^T+softmax).
__global__ __launch_bounds__(256)
void attn_kernel(const unsigned short* __restrict__ Q, const unsigned short* __restrict__ K,
                 const unsigned short* __restrict__ V, unsigned short* __restrict__ O) {
  __shared__ __align__(16) unsigned char VtRaw[2][8192];   // [buf][d=64][128B swizzled row]
  __shared__ __align__(16) unsigned short Ps[4][16][72];   // per-wave P (16x64), stride 144B

  const int bh = blockIdx.y;
  const int b  = bh >> 4, h = bh & 15;
  const int qt = blockIdx.x;
  const int tid = threadIdx.x, lane = tid & 63, wid = tid >> 6;
  const int fr = lane & 15, fg = lane >> 4;

  const size_t base = ((size_t)b * T_SEQ) * D_MODEL + h * HD;
  const unsigned short* Qb = Q + base;
  const unsigned short* Kb = K + base;
  const unsigned short* Vb = V + base;

  const int qrow0 = qt * 64 + wid * 16;

  // Q frags (A operand): Q[qrow0+fr][fg*8 + j], k-halves 0..31 / 32..63
  bf16x8 qf0, qf1;
  {
    const unsigned short* qp = Qb + (size_t)(qrow0 + fr) * D_MODEL + fg * 8;
    qf0 = *(const bf16x8*)qp;
    qf1 = *(const bf16x8*)(qp + 32);
  }

  // V staging assignment: thread -> kv-pair sg (0..31), d-range sd0..sd0+7
  const int sg  = tid >> 3;
  const int sd0 = (tid & 7) * 8;
  // write byte (within buf) for j: (sd0+j)*128 + ((sg*4) ^ (j<<4))   [(sd0+j)&7 == j]
  // read base for lane: row fr (+dblk*16), col kv: byte = d*128 + ((kv*2) ^ ((d&7)<<4))
  const int rrow = fr * 128;
  const int rxr  = (fr & 7) << 4;

  unsigned char* VtB = &VtRaw[0][0];

  // prologue: stage tile 0 into buf 0
  {
    bf16x8 ra = *(const bf16x8*)(Vb + (size_t)(2 * sg    ) * D_MODEL + sd0);
    bf16x8 rb = *(const bf16x8*)(Vb + (size_t)(2 * sg + 1) * D_MODEL + sd0);
#pragma unroll
    for (int j = 0; j < 8; ++j) {
      unsigned pk = (unsigned)(unsigned short)ra[j] | ((unsigned)(unsigned short)rb[j] << 16);
      *(unsigned*)(VtB + (sd0 + j) * 128 + ((sg * 4) ^ (j << 4))) = pk;
    }
  }

  float m_run[4], l_run[4];
  f32x4 acc[4];
#pragma unroll
  for (int r = 0; r < 4; r++) { m_run[r] = -INFINITY; l_run[r] = 0.f; }
#pragma unroll
  for (int d = 0; d < 4; d++) acc[d] = (f32x4){0.f, 0.f, 0.f, 0.f};

  const int ntiles = qt + 1;
  const float SCL = 0.18033688011f;   // (1/8) * log2(e)

  for (int kt = 0; kt < ntiles; ++kt) {
    __syncthreads();   // buf[kt&1] staged; prior reads of buf[(kt+1)&1] done
    const int kvb = kt * 64;
    const bool hn = (kt + 1 < ntiles);
    bf16x8 nva, nvb;
    if (hn) {   // issue next V tile loads early; consumed after compute
      nva = *(const bf16x8*)(Vb + (size_t)(kvb + 64 + 2 * sg    ) * D_MODEL + sd0);
      nvb = *(const bf16x8*)(Vb + (size_t)(kvb + 64 + 2 * sg + 1) * D_MODEL + sd0);
    }

    if (kvb <= qrow0 + 15) {   // wave-uniform: skip fully-masked tiles
      // ---- S = Q K^T (scaled to log2 domain) ----
      float s[4][4];
#pragma unroll
      for (int nt = 0; nt < 4; ++nt) {
        const unsigned short* kp = Kb + (size_t)(kvb + nt * 16 + fr) * D_MODEL + fg * 8;
        bf16x8 kf0 = *(const bf16x8*)kp;
        bf16x8 kf1 = *(const bf16x8*)(kp + 32);
        f32x4 sa = (f32x4){0.f, 0.f, 0.f, 0.f};
        sa = __builtin_amdgcn_mfma_f32_16x16x32_bf16(qf0, kf0, sa, 0, 0, 0);
        sa = __builtin_amdgcn_mfma_f32_16x16x32_bf16(qf1, kf1, sa, 0, 0, 0);
#pragma unroll
        for (int r = 0; r < 4; r++) s[nt][r] = sa[r] * SCL;
      }
      if (kvb + 63 > qrow0) {   // causal mask (diagonal region)
#pragma unroll
        for (int nt = 0; nt < 4; ++nt) {
          int col = kvb + nt * 16 + fr;
#pragma unroll
          for (int r = 0; r < 4; r++) {
            int row = qrow0 + fg * 4 + r;
            if (col > row) s[nt][r] = -INFINITY;
          }
        }
      }
      // ---- online softmax (row = qrow0 + fg*4 + r; cols over 16 fr lanes) ----
      float tm[4];
#pragma unroll
      for (int r = 0; r < 4; r++) tm[r] = fmaxf(fmaxf(s[0][r], s[1][r]), fmaxf(s[2][r], s[3][r]));
#pragma unroll
      for (int off = 1; off < 16; off <<= 1)
#pragma unroll
        for (int r = 0; r < 4; r++) tm[r] = fmaxf(tm[r], __shfl_xor(tm[r], off));

      float scale[4], rs[4];
#pragma unroll
      for (int r = 0; r < 4; r++) {
        float mn = fmaxf(m_run[r], tm[r]);
        scale[r] = exp2f(m_run[r] - mn);
        m_run[r] = mn;
        rs[r] = 0.f;
      }
      float pr[4][4];
#pragma unroll
      for (int nt = 0; nt < 4; nt++)
#pragma unroll
        for (int r = 0; r < 4; r++) { float p = exp2f(s[nt][r] - m_run[r]); pr[nt][r] = p; rs[r] += p; }
#pragma unroll
      for (int off = 1; off < 16; off <<= 1)
#pragma unroll
        for (int r = 0; r < 4; r++) rs[r] += __shfl_xor(rs[r], off);
#pragma unroll
      for (int r = 0; r < 4; r++) l_run[r] = l_run[r] * scale[r] + rs[r];
#pragma unroll
      for (int d = 0; d < 4; d++)
#pragma unroll
        for (int r = 0; r < 4; r++) acc[d][r] *= scale[r];

      // P -> per-wave LDS (C layout -> A layout transpose)
#pragma unroll
      for (int nt = 0; nt < 4; nt++)
#pragma unroll
        for (int r = 0; r < 4; r++)
          Ps[wid][fg * 4 + r][nt * 16 + fr] = f2bf(pr[nt][r]);

      // PV: acc[dblk] += P(16x64) * V(64x64); B-frag = Vt[dblk*16+fr][kv..kv+7]
      bf16x8 pa0 = *(const bf16x8*)&Ps[wid][fr][fg * 8];
      bf16x8 pa1 = *(const bf16x8*)&Ps[wid][fr][32 + fg * 8];
      const unsigned char* vbuf = VtB + (kt & 1) * 8192;
#pragma unroll
      for (int dblk = 0; dblk < 4; ++dblk) {
        bf16x8 b0 = *(const bf16x8*)(vbuf + rrow + dblk * 2048 + ((fg * 16) ^ rxr));
        bf16x8 b1 = *(const bf16x8*)(vbuf + rrow + dblk * 2048 + ((64 + fg * 16) ^ rxr));
        acc[dblk] = __builtin_amdgcn_mfma_f32_16x16x32_bf16(pa0, b0, acc[dblk], 0, 0, 0);
        acc[dblk] = __builtin_amdgcn_mfma_f32_16x16x32_bf16(pa1, b1, acc[dblk], 0, 0, 0);
      }
    }

    if (hn) {   // write next tile into alternate buffer
      unsigned char* nbuf = VtB + ((kt + 1) & 1) * 8192;
#pragma unroll
      for (int j = 0; j < 8; ++j) {
        unsigned pk = (unsigned)(unsigned short)nva[j] | ((unsigned)(unsigned short)nvb[j] << 16);
        *(unsigned*)(nbuf + (sd0 + j) * 128 + ((sg * 4) ^ (j << 4))) = pk;
      }
    }
  }

  // epilogue: O[b, q, h*64 + dblk*16 + fr], q = qrow0 + fg*4 + r
#pragma unroll
  for (int r = 0; r < 4; r++) {
    float rl = 1.0f / l_run[r];
    int row = qrow0 + fg * 4 + r;
    unsigned short* orow = O + ((size_t)b * T_SEQ + row) * D_MODEL + h * HD;
#pragma unroll
    for (int d = 0; d < 4; ++d)
      orow[d * 16 + fr] = f2bf(acc[d][r] * rl);
  }
}

// ---------------- launch ----------------
extern "C" void kernel_launch(void* const* d_in, const int* in_sizes, int n_in,
                              void* d_out, int out_size, void* d_ws, size_t ws_size,
                              hipStream_t stream) {
  const float* x   = (const float*)d_in[0];
  const int*   pos = (const int*)d_in[1];
  const float* Wq  = (const float*)d_in[2];
  const float* Wk  = (const float*)d_in[3];
  const float* Wv  = (const float*)d_in[4];
  const float* Wo  = (const float*)d_in[5];

  const size_t M  = (size_t)BATCH * T_SEQ;   // 4096
  const size_t DD = (size_t)D_MODEL * D_MODEL;

  char* ws = (char*)d_ws;
  unsigned short* xb  = (unsigned short*)ws; ws += M * D_MODEL * 2;
  unsigned short* Wqb = (unsigned short*)ws; ws += DD * 2;
  unsigned short* Wkb = (unsigned short*)ws; ws += DD * 2;
  unsigned short* Wvb = (unsigned short*)ws; ws += DD * 2;
  unsigned short* Wob = (unsigned short*)ws; ws += DD * 2;
  unsigned short* Qp  = (unsigned short*)ws; ws += M * D_MODEL * 2;
  unsigned short* Kp  = (unsigned short*)ws; ws += M * D_MODEL * 2;
  unsigned short* Vp  = (unsigned short*)ws; ws += M * D_MODEL * 2;
  unsigned short* Ob  = (unsigned short*)ws; ws += M * D_MODEL * 2;

  // casts
  int n4x = (int)(M * D_MODEL / 4);
  cast_kernel<<<(n4x + 255) / 256, 256, 0, stream>>>(x, xb, n4x);
  cast4_kernel<<<4096, 256, 0, stream>>>(Wq, Wk, Wv, Wo, Wqb, Wkb, Wvb, Wob);

  // fused QKV projection: grid.x = 3 matrices x 8 N-blocks
  gemm_bt<128, false><<<dim3(24, (unsigned)(M / 128)), 256, 0, stream>>>(
      xb, Wqb, Wkb, Wvb, Qp, Kp, Vp, (int)M, D_MODEL);

  // rope on Q,K in place
  int total = (int)(M * 512);
  rope_kernel<<<(total + 255) / 256, 256, 0, stream>>>(Qp, Kp, pos, total);

  // attention
  attn_kernel<<<dim3(T_SEQ / 64, BATCH * NH), 256, 0, stream>>>(Qp, Kp, Vp, Ob);

  // output projection (fp32 out), BN=64 for more blocks/CU
  gemm_bt<64, true><<<dim3(16, (unsigned)(M / 128)), 256, 0, stream>>>(
      Ob, Wob, Wob, Wob, d_out, d_out, d_out, (int)M, D_MODEL);
}

// Round 4
// 219.801 us; speedup vs baseline: 1.4704x; 1.0424x over previous
//
#include <hip/hip_runtime.h>
#include <math.h>
#include <stdint.h>

#define D_MODEL 1024
#define T_SEQ   2048
#define BATCH   2
#define NH      16
#define HD      64

typedef __attribute__((ext_vector_type(8))) short bf16x8;
typedef __attribute__((ext_vector_type(4))) float f32x4;

__device__ inline unsigned short f2bf(float f) {
  union { float f; unsigned int u; } v; v.f = f;
  unsigned int u = v.u;
  unsigned int r = u + 0x7fffu + ((u >> 16) & 1u);
  return (unsigned short)(r >> 16);
}
__device__ inline float bf2f(unsigned short s) {
  union { unsigned int u; float f; } v; v.u = ((unsigned int)s) << 16;
  return v.f;
}

// async global->LDS, 16B per lane, LDS dest = wave-uniform base + lane*16
#define GLDS16(g, l) __builtin_amdgcn_global_load_lds( \
  reinterpret_cast<const __attribute__((address_space(1))) void*>(reinterpret_cast<uintptr_t>(g)), \
  reinterpret_cast<__attribute__((address_space(3))) void*>(reinterpret_cast<uintptr_t>(l)), 16, 0, 0)

// ---------------- casts fp32 -> bf16 ----------------
__global__ void cast_kernel(const float* __restrict__ in, unsigned short* __restrict__ out, int n4) {
  int id = blockIdx.x * blockDim.x + threadIdx.x;
  if (id >= n4) return;
  float4 v = ((const float4*)in)[id];
  ushort4 o;
  o.x = f2bf(v.x); o.y = f2bf(v.y); o.z = f2bf(v.z); o.w = f2bf(v.w);
  ((ushort4*)out)[id] = o;
}

__global__ void cast4_kernel(const float* __restrict__ s0, const float* __restrict__ s1,
                             const float* __restrict__ s2, const float* __restrict__ s3,
                             unsigned short* __restrict__ d0, unsigned short* __restrict__ d1,
                             unsigned short* __restrict__ d2, unsigned short* __restrict__ d3) {
  int id = blockIdx.x * blockDim.x + threadIdx.x;   // 4 * 2^18
  int m = id >> 18, r = id & ((1 << 18) - 1);
  const float* s = (m == 0) ? s0 : (m == 1) ? s1 : (m == 2) ? s2 : s3;
  unsigned short* dd = (m == 0) ? d0 : (m == 1) ? d1 : (m == 2) ? d2 : d3;
  float4 v = ((const float4*)s)[r];
  ushort4 o;
  o.x = f2bf(v.x); o.y = f2bf(v.y); o.z = f2bf(v.z); o.w = f2bf(v.w);
  ((ushort4*)dd)[r] = o;
}

// ---------------- GEMM: C[M,1024] = A[M,K] * B[1024,K]^T (bf16, fp32 acc) ----------------
template<int BN, bool F32OUT>
__global__ __launch_bounds__(256)
void gemm_bt(const unsigned short* __restrict__ A,
             const unsigned short* __restrict__ B0, const unsigned short* __restrict__ B1,
             const unsigned short* __restrict__ B2,
             void* __restrict__ C0, void* __restrict__ C1, void* __restrict__ C2,
             int M, int K) {
  constexpr int NPM = 1024 / BN;
  constexpr int NWC = BN / 64;
  constexpr int MI  = 2 * NWC;
  __shared__ __align__(16) unsigned short As[128 * 32];
  __shared__ __align__(16) unsigned short Bs[BN * 32];

  const int tid = threadIdx.x, lane = tid & 63, wid = tid >> 6;
  const int wr = wid / NWC, wc = wid % NWC;
  const int bx = blockIdx.x;
  const int mat = bx / NPM;
  const int bn = (bx % NPM) * BN;
  const int bm = blockIdx.y * 128;
  const unsigned short* B = (mat == 0) ? B0 : (mat == 1) ? B1 : B2;
  void* C = (mat == 0) ? C0 : (mat == 1) ? C1 : C2;

  f32x4 acc[MI][4];
#pragma unroll
  for (int i = 0; i < MI; i++)
#pragma unroll
    for (int j = 0; j < 4; j++) acc[i][j] = (f32x4){0.f, 0.f, 0.f, 0.f};

  const int fr = lane & 15, fg = lane >> 4;
  const int lrow = lane >> 2, lcol = (lane & 3) * 8;

  for (int kb = 0; kb < K; kb += 32) {
#pragma unroll
    for (int c = 0; c < 2; ++c) {
      int rb = wid * 32 + c * 16;
      GLDS16(A + (size_t)(bm + rb + lrow) * K + kb + lcol, As + rb * 32);
    }
#pragma unroll
    for (int c = 0; c < BN / 64; ++c) {
      int rb = wid * (BN / 4) + c * 16;
      GLDS16(B + (size_t)(bn + rb + lrow) * K + kb + lcol, Bs + rb * 32);
    }
    __syncthreads();
    bf16x8 a[MI], bq[4];
#pragma unroll
    for (int mi = 0; mi < MI; mi++)
      a[mi] = *(const bf16x8*)&As[(wr * (16 * MI) + mi * 16 + fr) * 32 + fg * 8];
#pragma unroll
    for (int ni = 0; ni < 4; ni++)
      bq[ni] = *(const bf16x8*)&Bs[(wc * 64 + ni * 16 + fr) * 32 + fg * 8];
#pragma unroll
    for (int mi = 0; mi < MI; mi++)
#pragma unroll
      for (int ni = 0; ni < 4; ni++)
        acc[mi][ni] = __builtin_amdgcn_mfma_f32_16x16x32_bf16(a[mi], bq[ni], acc[mi][ni], 0, 0, 0);
    __syncthreads();
  }

  const int fc = lane & 15, fq = lane >> 4;
#pragma unroll
  for (int mi = 0; mi < MI; mi++)
#pragma unroll
    for (int ni = 0; ni < 4; ni++) {
      int col = bn + wc * 64 + ni * 16 + fc;
#pragma unroll
      for (int r = 0; r < 4; r++) {
        int row = bm + wr * (16 * MI) + mi * 16 + fq * 4 + r;
        if (F32OUT) ((float*)C)[(size_t)row * 1024 + col] = acc[mi][ni][r];
        else ((unsigned short*)C)[(size_t)row * 1024 + col] = f2bf(acc[mi][ni][r]);
      }
    }
}

// ---------------- RoPE in-place on bf16 (b,t,o) for Q and K ----------------
__global__ void rope_kernel(unsigned short* __restrict__ Qp, unsigned short* __restrict__ Kp,
                            const int* __restrict__ pos, int total) {
  int id = blockIdx.x * blockDim.x + threadIdx.x;
  if (id >= total) return;
  int m  = id >> 9;
  int p2 = id & 511;
  int p  = p2 & 31;
  float posf = (float)pos[m];
  float inv  = powf(10000.0f, (float)(-2 * p) / 64.0f);
  float ang  = posf * inv;
  float sn, cs;
  sincosf(ang, &sn, &cs);
  size_t off = (size_t)m * D_MODEL + 2 * p2;
  float q1 = bf2f(Qp[off]), q2 = bf2f(Qp[off + 1]);
  Qp[off]     = f2bf(q1 * cs - q2 * sn);
  Qp[off + 1] = f2bf(q1 * sn + q2 * cs);
  float k1 = bf2f(Kp[off]), k2 = bf2f(Kp[off + 1]);
  Kp[off]     = f2bf(k1 * cs - k2 * sn);
  Kp[off + 1] = f2bf(k1 * sn + k2 * cs);
}

// ---------------- Flash attention, causal, bf16 MFMA ----------------
// Verified round-3 structure (S=QK^T, C layout col=fr,row=fg*4+r; P via LDS;
// Vt transposed-in-LDS). Round-4: 32 q-rows/wave (2 q-blocks), K staged once
// per block via global_load_lds in fragment-major layout [nt][half][lane][16B]
// (conflict-free per-lane ds_read_b128, 1/4 global K traffic, async a full
// tile ahead), Vt write swizzle += (d>>3) term (write now 2-way = free),
// Ps swizzle ^((row>>2)<<5) (write spread over all banks), reversed qt
// dispatch so longest blocks start first.
__global__ __launch_bounds__(256)
void attn_kernel(const unsigned short* __restrict__ Q, const unsigned short* __restrict__ K,
                 const unsigned short* __restrict__ V, unsigned short* __restrict__ O) {
  __shared__ __align__(16) unsigned char KsRaw[2][8192];   // [buf][idx=nt*2+half][lane][16B]
  __shared__ __align__(16) unsigned char VtRaw[2][8192];   // [buf][d][128B swizzled row]
  __shared__ __align__(16) unsigned char PsRaw[4][2][2304]; // [wave][qb][row*144 swizzled]

  const int bh = blockIdx.y;
  const int b  = bh >> 4, h = bh & 15;
  const int qt = (int)(gridDim.x - 1 - blockIdx.x);   // reversed: long blocks first
  const int tid = threadIdx.x, lane = tid & 63, wid = tid >> 6;
  const int fr = lane & 15, fg = lane >> 4;

  const size_t base = ((size_t)b * T_SEQ) * D_MODEL + h * HD;
  const unsigned short* Qb = Q + base;
  const unsigned short* Kb = K + base;
  const unsigned short* Vb = V + base;

  const int qrow0 = qt * 128 + wid * 32;

  // Q frags: Q[qrow0 + qb*16 + fr][fg*8 + j], k-halves 0..31 / 32..63
  bf16x8 qf[2][2];
#pragma unroll
  for (int qb = 0; qb < 2; ++qb) {
    const unsigned short* qp = Qb + (size_t)(qrow0 + qb * 16 + fr) * D_MODEL + fg * 8;
    qf[qb][0] = *(const bf16x8*)qp;
    qf[qb][1] = *(const bf16x8*)(qp + 32);
  }

  // V staging: thread -> kv-pair sg (0..31), d-range sd0..sd0+7, sx = sd0>>3
  const int sg  = tid >> 3;
  const int sd0 = (tid & 7) * 8;
  const int sx  = tid & 7;
  // element (kv,d) at byte d*128 + ((kv*2) ^ X(d)),  X(d) = ((d&7)^((d>>3)&7))<<4

#define STAGE_K(kvbase, buf) do { \
    _Pragma("unroll") \
    for (int c_ = 0; c_ < 2; ++c_) { \
      int idx_ = wid * 2 + c_; \
      int nt_ = idx_ >> 1, hf_ = idx_ & 1; \
      GLDS16(Kb + (size_t)((kvbase) + nt_ * 16 + fr) * D_MODEL + hf_ * 32 + fg * 8, \
             &KsRaw[buf][idx_ * 1024]); \
    } \
  } while (0)

#define STAGE_V_WRITE(ra_, rb_, bufp_) do { \
    _Pragma("unroll") \
    for (int j_ = 0; j_ < 8; ++j_) { \
      unsigned pk_ = (unsigned)(unsigned short)(ra_)[j_] | ((unsigned)(unsigned short)(rb_)[j_] << 16); \
      *(unsigned*)((bufp_) + (sd0 + j_) * 128 + ((sg * 4) ^ ((j_ ^ sx) << 4))) = pk_; \
    } \
  } while (0)

  // prologue: stage K tile 0 (async) + V tile 0 into buf 0
  STAGE_K(0, 0);
  {
    bf16x8 ra = *(const bf16x8*)(Vb + (size_t)(2 * sg    ) * D_MODEL + sd0);
    bf16x8 rb = *(const bf16x8*)(Vb + (size_t)(2 * sg + 1) * D_MODEL + sd0);
    STAGE_V_WRITE(ra, rb, &VtRaw[0][0]);
  }

  float m_run[2][4], l_run[2][4];
  f32x4 acc[2][4];
#pragma unroll
  for (int qb = 0; qb < 2; ++qb)
#pragma unroll
    for (int r = 0; r < 4; ++r) { m_run[qb][r] = -INFINITY; l_run[qb][r] = 0.f; }
#pragma unroll
  for (int qb = 0; qb < 2; ++qb)
#pragma unroll
    for (int d = 0; d < 4; ++d) acc[qb][d] = (f32x4){0.f, 0.f, 0.f, 0.f};

  const int ntk = 2 * qt + 2;
  const float SCL = 0.18033688011f;   // (1/8) * log2(e)
  unsigned char* PsW[2] = { &PsRaw[wid][0][0], &PsRaw[wid][1][0] };

  for (int kt = 0; kt < ntk; ++kt) {
    __syncthreads();   // buf[kt&1] (K async + V writes) ready; prior reads of buf[kt+1&1] done
    const int kvb = kt * 64;
    const bool hn = (kt + 1 < ntk);
    bf16x8 nva, nvb;
    if (hn) {
      STAGE_K(kvb + 64, (kt + 1) & 1);   // async, lands before next barrier
      nva = *(const bf16x8*)(Vb + (size_t)(kvb + 64 + 2 * sg    ) * D_MODEL + sd0);
      nvb = *(const bf16x8*)(Vb + (size_t)(kvb + 64 + 2 * sg + 1) * D_MODEL + sd0);
    }

    if (kvb <= qrow0 + 31) {   // wave-uniform skip of fully-masked tiles
      const unsigned char* kbuf = &KsRaw[kt & 1][0];
      // ---- S = Q K^T ----
      f32x4 st[2][4];
#pragma unroll
      for (int nt = 0; nt < 4; ++nt) {
        bf16x8 kf0 = *(const bf16x8*)(kbuf + (nt * 2    ) * 1024 + lane * 16);
        bf16x8 kf1 = *(const bf16x8*)(kbuf + (nt * 2 + 1) * 1024 + lane * 16);
#pragma unroll
        for (int qb = 0; qb < 2; ++qb) {
          f32x4 sa = (f32x4){0.f, 0.f, 0.f, 0.f};
          sa = __builtin_amdgcn_mfma_f32_16x16x32_bf16(qf[qb][0], kf0, sa, 0, 0, 0);
          sa = __builtin_amdgcn_mfma_f32_16x16x32_bf16(qf[qb][1], kf1, sa, 0, 0, 0);
          st[qb][nt] = sa;
        }
      }
      const bool domask = (kvb + 63 > qrow0);
      // ---- per-q-block softmax + P write ----
#pragma unroll
      for (int qb = 0; qb < 2; ++qb) {
        float p[4][4];
#pragma unroll
        for (int nt = 0; nt < 4; ++nt)
#pragma unroll
          for (int r = 0; r < 4; ++r) p[nt][r] = st[qb][nt][r] * SCL;
        if (domask) {
          int qrow = qrow0 + qb * 16;
#pragma unroll
          for (int nt = 0; nt < 4; ++nt) {
            int col = kvb + nt * 16 + fr;
#pragma unroll
            for (int r = 0; r < 4; ++r)
              if (col > qrow + fg * 4 + r) p[nt][r] = -INFINITY;
          }
        }
        float tm[4];
#pragma unroll
        for (int r = 0; r < 4; ++r) tm[r] = fmaxf(fmaxf(p[0][r], p[1][r]), fmaxf(p[2][r], p[3][r]));
#pragma unroll
        for (int off = 1; off < 16; off <<= 1)
#pragma unroll
          for (int r = 0; r < 4; ++r) tm[r] = fmaxf(tm[r], __shfl_xor(tm[r], off));
        float scale[4], rs[4];
#pragma unroll
        for (int r = 0; r < 4; ++r) {
          float mn = fmaxf(m_run[qb][r], tm[r]);
          scale[r] = exp2f(m_run[qb][r] - mn);
          m_run[qb][r] = mn;
          rs[r] = 0.f;
        }
#pragma unroll
        for (int nt = 0; nt < 4; ++nt)
#pragma unroll
          for (int r = 0; r < 4; ++r) {
            float pv = exp2f(p[nt][r] - m_run[qb][r]);
            p[nt][r] = pv; rs[r] += pv;
          }
#pragma unroll
        for (int off = 1; off < 16; off <<= 1)
#pragma unroll
          for (int r = 0; r < 4; ++r) rs[r] += __shfl_xor(rs[r], off);
#pragma unroll
        for (int r = 0; r < 4; ++r) l_run[qb][r] = l_run[qb][r] * scale[r] + rs[r];
#pragma unroll
        for (int d = 0; d < 4; ++d)
#pragma unroll
          for (int r = 0; r < 4; ++r) acc[qb][d][r] *= scale[r];
        // P -> LDS, swizzled: byte(row,col) = row*144 + ((col*2) ^ ((row>>2)<<5))
#pragma unroll
        for (int nt = 0; nt < 4; ++nt)
#pragma unroll
          for (int r = 0; r < 4; ++r)
            *(unsigned short*)(PsW[qb] + (fg * 4 + r) * 144 + ((nt * 32 + fr * 2) ^ (fg << 5)))
                = f2bf(p[nt][r]);
      }

      // ---- PV: acc[qb][dblk] += P * V ----
      bf16x8 pa[2][2];
#pragma unroll
      for (int qb = 0; qb < 2; ++qb)
#pragma unroll
        for (int hf = 0; hf < 2; ++hf)
          pa[qb][hf] = *(const bf16x8*)(PsW[qb] + fr * 144 + ((hf * 64 + fg * 16) ^ ((fr >> 2) << 5)));
      const unsigned char* vbuf = &VtRaw[kt & 1][0];
#pragma unroll
      for (int dblk = 0; dblk < 4; ++dblk) {
        int xr = ((fr & 7) ^ ((dblk * 2 + (fr >> 3)) & 7)) << 4;
        const unsigned char* vp = vbuf + (dblk * 16 + fr) * 128;
        bf16x8 b0 = *(const bf16x8*)(vp + ((fg * 16) ^ xr));
        bf16x8 b1 = *(const bf16x8*)(vp + ((64 + fg * 16) ^ xr));
        acc[0][dblk] = __builtin_amdgcn_mfma_f32_16x16x32_bf16(pa[0][0], b0, acc[0][dblk], 0, 0, 0);
        acc[1][dblk] = __builtin_amdgcn_mfma_f32_16x16x32_bf16(pa[1][0], b0, acc[1][dblk], 0, 0, 0);
        acc[0][dblk] = __builtin_amdgcn_mfma_f32_16x16x32_bf16(pa[0][1], b1, acc[0][dblk], 0, 0, 0);
        acc[1][dblk] = __builtin_amdgcn_mfma_f32_16x16x32_bf16(pa[1][1], b1, acc[1][dblk], 0, 0, 0);
      }
    }

    if (hn) STAGE_V_WRITE(nva, nvb, &VtRaw[(kt + 1) & 1][0]);
  }
#undef STAGE_K
#undef STAGE_V_WRITE

  // epilogue: O[b, q, h*64 + dblk*16 + fr], q = qrow0 + qb*16 + fg*4 + r
#pragma unroll
  for (int qb = 0; qb < 2; ++qb)
#pragma unroll
    for (int r = 0; r < 4; ++r) {
      float rl = 1.0f / l_run[qb][r];
      int row = qrow0 + qb * 16 + fg * 4 + r;
      unsigned short* orow = O + ((size_t)b * T_SEQ + row) * D_MODEL + h * HD;
#pragma unroll
      for (int d = 0; d < 4; ++d)
        orow[d * 16 + fr] = f2bf(acc[qb][d][r] * rl);
    }
}

// ---------------- launch ----------------
extern "C" void kernel_launch(void* const* d_in, const int* in_sizes, int n_in,
                              void* d_out, int out_size, void* d_ws, size_t ws_size,
                              hipStream_t stream) {
  const float* x   = (const float*)d_in[0];
  const int*   pos = (const int*)d_in[1];
  const float* Wq  = (const float*)d_in[2];
  const float* Wk  = (const float*)d_in[3];
  const float* Wv  = (const float*)d_in[4];
  const float* Wo  = (const float*)d_in[5];

  const size_t M  = (size_t)BATCH * T_SEQ;   // 4096
  const size_t DD = (size_t)D_MODEL * D_MODEL;

  char* ws = (char*)d_ws;
  unsigned short* xb  = (unsigned short*)ws; ws += M * D_MODEL * 2;
  unsigned short* Wqb = (unsigned short*)ws; ws += DD * 2;
  unsigned short* Wkb = (unsigned short*)ws; ws += DD * 2;
  unsigned short* Wvb = (unsigned short*)ws; ws += DD * 2;
  unsigned short* Wob = (unsigned short*)ws; ws += DD * 2;
  unsigned short* Qp  = (unsigned short*)ws; ws += M * D_MODEL * 2;
  unsigned short* Kp  = (unsigned short*)ws; ws += M * D_MODEL * 2;
  unsigned short* Vp  = (unsigned short*)ws; ws += M * D_MODEL * 2;
  unsigned short* Ob  = (unsigned short*)ws; ws += M * D_MODEL * 2;

  // casts
  int n4x = (int)(M * D_MODEL / 4);
  cast_kernel<<<(n4x + 255) / 256, 256, 0, stream>>>(x, xb, n4x);
  cast4_kernel<<<4096, 256, 0, stream>>>(Wq, Wk, Wv, Wo, Wqb, Wkb, Wvb, Wob);

  // fused QKV projection
  gemm_bt<128, false><<<dim3(24, (unsigned)(M / 128)), 256, 0, stream>>>(
      xb, Wqb, Wkb, Wvb, Qp, Kp, Vp, (int)M, D_MODEL);

  // rope on Q,K in place
  int total = (int)(M * 512);
  rope_kernel<<<(total + 255) / 256, 256, 0, stream>>>(Qp, Kp, pos, total);

  // attention: 128 q-rows/block, reversed qt for load balance
  attn_kernel<<<dim3(T_SEQ / 128, BATCH * NH), 256, 0, stream>>>(Qp, Kp, Vp, Ob);

  // output projection (fp32 out)
  gemm_bt<64, true><<<dim3(16, (unsigned)(M / 128)), 256, 0, stream>>>(
      Ob, Wob, Wob, Wob, d_out, d_out, d_out, (int)M, D_MODEL);
}

// Round 5
// 175.922 us; speedup vs baseline: 1.8372x; 1.2494x over previous
//
#include <hip/hip_runtime.h>
#include <math.h>
#include <stdint.h>

#define D_MODEL 1024
#define T_SEQ   2048
#define BATCH   2
#define NH      16
#define HD      64

typedef __attribute__((ext_vector_type(8))) short bf16x8;
typedef __attribute__((ext_vector_type(4))) float f32x4;

__device__ inline unsigned short f2bf(float f) {
  union { float f; unsigned int u; } v; v.f = f;
  unsigned int u = v.u;
  unsigned int r = u + 0x7fffu + ((u >> 16) & 1u);
  return (unsigned short)(r >> 16);
}
__device__ inline float bf2f(unsigned short s) {
  union { unsigned int u; float f; } v; v.u = ((unsigned int)s) << 16;
  return v.f;
}

// async global->LDS, 16B per lane, LDS dest = wave-uniform base + lane*16
#define GLDS16(g, l) __builtin_amdgcn_global_load_lds( \
  reinterpret_cast<const __attribute__((address_space(1))) void*>(reinterpret_cast<uintptr_t>(g)), \
  reinterpret_cast<__attribute__((address_space(3))) void*>(reinterpret_cast<uintptr_t>(l)), 16, 0, 0)

// P-quad store: rows r..r+3 at va+{0,144,288,432}; cvt_pk pairs (r0,r1),(r2,r3)
#define PSTORE(va_, p0_, p1_, p2_, p3_) do { \
  unsigned t0_, t1_; \
  asm volatile( \
    "v_cvt_pk_bf16_f32 %0, %3, %4\n\t" \
    "v_cvt_pk_bf16_f32 %1, %5, %6\n\t" \
    "ds_write_b16 %2, %0\n\t" \
    "ds_write_b16_d16_hi %2, %0 offset:144\n\t" \
    "ds_write_b16 %2, %1 offset:288\n\t" \
    "ds_write_b16_d16_hi %2, %1 offset:432" \
    : "=&v"(t0_), "=&v"(t1_) \
    : "v"(va_), "v"(p0_), "v"(p1_), "v"(p2_), "v"(p3_) \
    : "memory"); \
} while (0)

// ---------------- casts fp32 -> bf16 ----------------
__global__ void cast_kernel(const float* __restrict__ in, unsigned short* __restrict__ out, int n4) {
  int id = blockIdx.x * blockDim.x + threadIdx.x;
  if (id >= n4) return;
  float4 v = ((const float4*)in)[id];
  ushort4 o;
  o.x = f2bf(v.x); o.y = f2bf(v.y); o.z = f2bf(v.z); o.w = f2bf(v.w);
  ((ushort4*)out)[id] = o;
}

__global__ void cast4_kernel(const float* __restrict__ s0, const float* __restrict__ s1,
                             const float* __restrict__ s2, const float* __restrict__ s3,
                             unsigned short* __restrict__ d0, unsigned short* __restrict__ d1,
                             unsigned short* __restrict__ d2, unsigned short* __restrict__ d3) {
  int id = blockIdx.x * blockDim.x + threadIdx.x;   // 4 * 2^18
  int m = id >> 18, r = id & ((1 << 18) - 1);
  const float* s = (m == 0) ? s0 : (m == 1) ? s1 : (m == 2) ? s2 : s3;
  unsigned short* dd = (m == 0) ? d0 : (m == 1) ? d1 : (m == 2) ? d2 : d3;
  float4 v = ((const float4*)s)[r];
  ushort4 o;
  o.x = f2bf(v.x); o.y = f2bf(v.y); o.z = f2bf(v.z); o.w = f2bf(v.w);
  ((ushort4*)dd)[r] = o;
}

// ---------------- GEMM: C[M,1024] = A[M,K] * B[1024,K]^T (bf16, fp32 acc) ----------------
template<int BN, bool F32OUT>
__global__ __launch_bounds__(256)
void gemm_bt(const unsigned short* __restrict__ A,
             const unsigned short* __restrict__ B0, const unsigned short* __restrict__ B1,
             const unsigned short* __restrict__ B2,
             void* __restrict__ C0, void* __restrict__ C1, void* __restrict__ C2,
             int M, int K) {
  constexpr int NPM = 1024 / BN;
  constexpr int NWC = BN / 64;
  constexpr int MI  = 2 * NWC;
  __shared__ __align__(16) unsigned short As[128 * 32];
  __shared__ __align__(16) unsigned short Bs[BN * 32];

  const int tid = threadIdx.x, lane = tid & 63, wid = tid >> 6;
  const int wr = wid / NWC, wc = wid % NWC;
  const int bx = blockIdx.x;
  const int mat = bx / NPM;
  const int bn = (bx % NPM) * BN;
  const int bm = blockIdx.y * 128;
  const unsigned short* B = (mat == 0) ? B0 : (mat == 1) ? B1 : B2;
  void* C = (mat == 0) ? C0 : (mat == 1) ? C1 : C2;

  f32x4 acc[MI][4];
#pragma unroll
  for (int i = 0; i < MI; i++)
#pragma unroll
    for (int j = 0; j < 4; j++) acc[i][j] = (f32x4){0.f, 0.f, 0.f, 0.f};

  const int fr = lane & 15, fg = lane >> 4;
  const int lrow = lane >> 2, lcol = (lane & 3) * 8;

  for (int kb = 0; kb < K; kb += 32) {
#pragma unroll
    for (int c = 0; c < 2; ++c) {
      int rb = wid * 32 + c * 16;
      GLDS16(A + (size_t)(bm + rb + lrow) * K + kb + lcol, As + rb * 32);
    }
#pragma unroll
    for (int c = 0; c < BN / 64; ++c) {
      int rb = wid * (BN / 4) + c * 16;
      GLDS16(B + (size_t)(bn + rb + lrow) * K + kb + lcol, Bs + rb * 32);
    }
    __syncthreads();
    bf16x8 a[MI], bq[4];
#pragma unroll
    for (int mi = 0; mi < MI; mi++)
      a[mi] = *(const bf16x8*)&As[(wr * (16 * MI) + mi * 16 + fr) * 32 + fg * 8];
#pragma unroll
    for (int ni = 0; ni < 4; ni++)
      bq[ni] = *(const bf16x8*)&Bs[(wc * 64 + ni * 16 + fr) * 32 + fg * 8];
#pragma unroll
    for (int mi = 0; mi < MI; mi++)
#pragma unroll
      for (int ni = 0; ni < 4; ni++)
        acc[mi][ni] = __builtin_amdgcn_mfma_f32_16x16x32_bf16(a[mi], bq[ni], acc[mi][ni], 0, 0, 0);
    __syncthreads();
  }

  const int fc = lane & 15, fq = lane >> 4;
#pragma unroll
  for (int mi = 0; mi < MI; mi++)
#pragma unroll
    for (int ni = 0; ni < 4; ni++) {
      int col = bn + wc * 64 + ni * 16 + fc;
#pragma unroll
      for (int r = 0; r < 4; r++) {
        int row = bm + wr * (16 * MI) + mi * 16 + fq * 4 + r;
        if (F32OUT) ((float*)C)[(size_t)row * 1024 + col] = acc[mi][ni][r];
        else ((unsigned short*)C)[(size_t)row * 1024 + col] = f2bf(acc[mi][ni][r]);
      }
    }
}

// ---------------- RoPE in-place; Q additionally pre-scaled by (1/8)*log2e ----------------
__global__ void rope_kernel(unsigned short* __restrict__ Qp, unsigned short* __restrict__ Kp,
                            const int* __restrict__ pos, int total) {
  const float SCL = 0.18033688011f;   // (1/8) * log2(e): folds attn scale into Q
  int id = blockIdx.x * blockDim.x + threadIdx.x;
  if (id >= total) return;
  int m  = id >> 9;
  int p2 = id & 511;
  int p  = p2 & 31;
  float posf = (float)pos[m];
  float inv  = powf(10000.0f, (float)(-2 * p) / 64.0f);
  float ang  = posf * inv;
  float sn, cs;
  sincosf(ang, &sn, &cs);
  size_t off = (size_t)m * D_MODEL + 2 * p2;
  float q1 = bf2f(Qp[off]), q2 = bf2f(Qp[off + 1]);
  Qp[off]     = f2bf((q1 * cs - q2 * sn) * SCL);
  Qp[off + 1] = f2bf((q1 * sn + q2 * cs) * SCL);
  float k1 = bf2f(Kp[off]), k2 = bf2f(Kp[off + 1]);
  Kp[off]     = f2bf(k1 * cs - k2 * sn);
  Kp[off + 1] = f2bf(k1 * sn + k2 * cs);
}

// ---------------- Flash attention, causal, bf16 MFMA ----------------
// R4-verified layouts (K fragment-major LDS via global_load_lds; Vt transposed
// + swizzled; Ps row-major 144B swizzled). R5: defer-max (THR=8) + deferred
// l-sum => steady-state tiles have ZERO cross-lane ops; P-store via
// v_cvt_pk_bf16_f32 + ds_write_b16/_d16_hi with precomputed addresses;
// setprio around MFMA clusters.
__global__ __launch_bounds__(256)
void attn_kernel(const unsigned short* __restrict__ Q, const unsigned short* __restrict__ K,
                 const unsigned short* __restrict__ V, unsigned short* __restrict__ O) {
  __shared__ __align__(16) unsigned char KsRaw[2][8192];    // [buf][idx=nt*2+half][lane][16B]
  __shared__ __align__(16) unsigned char VtRaw[2][8192];    // [buf][d][128B swizzled row]
  __shared__ __align__(16) unsigned char PsRaw[4][2][2304]; // [wave][qb][row*144 swizzled]

  const int bh = blockIdx.y;
  const int b  = bh >> 4, h = bh & 15;
  const int qt = (int)(gridDim.x - 1 - blockIdx.x);   // reversed: long blocks first
  const int tid = threadIdx.x, lane = tid & 63, wid = tid >> 6;
  const int fr = lane & 15, fg = lane >> 4;

  const size_t base = ((size_t)b * T_SEQ) * D_MODEL + h * HD;
  const unsigned short* Qb = Q + base;
  const unsigned short* Kb = K + base;
  const unsigned short* Vb = V + base;

  const int qrow0 = qt * 128 + wid * 32;

  // Q frags (pre-scaled in rope): Q[qrow0 + qb*16 + fr][fg*8 + j]
  bf16x8 qf[2][2];
#pragma unroll
  for (int qb = 0; qb < 2; ++qb) {
    const unsigned short* qp = Qb + (size_t)(qrow0 + qb * 16 + fr) * D_MODEL + fg * 8;
    qf[qb][0] = *(const bf16x8*)qp;
    qf[qb][1] = *(const bf16x8*)(qp + 32);
  }

  // V staging: thread -> kv-pair sg (0..31), d-range sd0..sd0+7
  const int sg  = tid >> 3;
  const int sd0 = (tid & 7) * 8;
  const int sx  = tid & 7;

#define STAGE_K(kvbase, buf) do { \
    _Pragma("unroll") \
    for (int c_ = 0; c_ < 2; ++c_) { \
      int idx_ = wid * 2 + c_; \
      int nt_ = idx_ >> 1, hf_ = idx_ & 1; \
      GLDS16(Kb + (size_t)((kvbase) + nt_ * 16 + fr) * D_MODEL + hf_ * 32 + fg * 8, \
             &KsRaw[buf][idx_ * 1024]); \
    } \
  } while (0)

#define STAGE_V_WRITE(ra_, rb_, bufp_) do { \
    _Pragma("unroll") \
    for (int j_ = 0; j_ < 8; ++j_) { \
      unsigned pk_ = (unsigned)(unsigned short)(ra_)[j_] | ((unsigned)(unsigned short)(rb_)[j_] << 16); \
      *(unsigned*)((bufp_) + (sd0 + j_) * 128 + ((sg * 4) ^ ((j_ ^ sx) << 4))) = pk_; \
    } \
  } while (0)

  // prologue: stage K tile 0 (async) + V tile 0 into buf 0
  STAGE_K(0, 0);
  {
    bf16x8 ra = *(const bf16x8*)(Vb + (size_t)(2 * sg    ) * D_MODEL + sd0);
    bf16x8 rb = *(const bf16x8*)(Vb + (size_t)(2 * sg + 1) * D_MODEL + sd0);
    STAGE_V_WRITE(ra, rb, &VtRaw[0][0]);
  }

  // precomputed P-store addresses (LDS offsets), row-invariant part:
  // va = PsRaw[wid][qb] + fg*576 + ((nt*32 + fr*2) ^ (fg<<5)); rows add 0/144/288/432
  unsigned pva[2][4];
  {
    unsigned psb = (unsigned)(uintptr_t)(void*)&PsRaw[wid][0][0];
#pragma unroll
    for (int qb = 0; qb < 2; ++qb)
#pragma unroll
      for (int nt = 0; nt < 4; ++nt)
        pva[qb][nt] = psb + qb * 2304 + fg * 576 + (unsigned)((nt * 32 + fr * 2) ^ (fg << 5));
  }

  float m_run[2][4], l_part[2][4];
  f32x4 acc[2][4];
#pragma unroll
  for (int qb = 0; qb < 2; ++qb)
#pragma unroll
    for (int r = 0; r < 4; ++r) { m_run[qb][r] = -INFINITY; l_part[qb][r] = 0.f; }
#pragma unroll
  for (int qb = 0; qb < 2; ++qb)
#pragma unroll
    for (int d = 0; d < 4; ++d) acc[qb][d] = (f32x4){0.f, 0.f, 0.f, 0.f};

  const int ntk = 2 * qt + 2;

  for (int kt = 0; kt < ntk; ++kt) {
    __syncthreads();   // buf[kt&1] (K async + V ds_writes) ready
    const int kvb = kt * 64;
    const bool hn = (kt + 1 < ntk);
    bf16x8 nva, nvb;
    if (hn) {
      STAGE_K(kvb + 64, (kt + 1) & 1);
      nva = *(const bf16x8*)(Vb + (size_t)(kvb + 64 + 2 * sg    ) * D_MODEL + sd0);
      nvb = *(const bf16x8*)(Vb + (size_t)(kvb + 64 + 2 * sg + 1) * D_MODEL + sd0);
    }

    if (kvb <= qrow0 + 31) {   // wave-uniform skip of fully-masked tiles
      const unsigned char* kbuf = &KsRaw[kt & 1][0];
      // ---- S = Q K^T (Q pre-scaled: S already in exp2 domain) ----
      f32x4 st[2][4];
      __builtin_amdgcn_s_setprio(1);
#pragma unroll
      for (int nt = 0; nt < 4; ++nt) {
        bf16x8 kf0 = *(const bf16x8*)(kbuf + (nt * 2    ) * 1024 + lane * 16);
        bf16x8 kf1 = *(const bf16x8*)(kbuf + (nt * 2 + 1) * 1024 + lane * 16);
#pragma unroll
        for (int qb = 0; qb < 2; ++qb) {
          f32x4 sa = (f32x4){0.f, 0.f, 0.f, 0.f};
          sa = __builtin_amdgcn_mfma_f32_16x16x32_bf16(qf[qb][0], kf0, sa, 0, 0, 0);
          sa = __builtin_amdgcn_mfma_f32_16x16x32_bf16(qf[qb][1], kf1, sa, 0, 0, 0);
          st[qb][nt] = sa;
        }
      }
      __builtin_amdgcn_s_setprio(0);

      float p[2][4][4];
#pragma unroll
      for (int qb = 0; qb < 2; ++qb)
#pragma unroll
        for (int nt = 0; nt < 4; ++nt)
#pragma unroll
          for (int r = 0; r < 4; ++r) p[qb][nt][r] = st[qb][nt][r];
      if (kvb + 63 > qrow0) {   // causal mask (diagonal region only)
#pragma unroll
        for (int qb = 0; qb < 2; ++qb) {
          int qrow = qrow0 + qb * 16;
#pragma unroll
          for (int nt = 0; nt < 4; ++nt) {
            int col = kvb + nt * 16 + fr;
#pragma unroll
            for (int r = 0; r < 4; ++r)
              if (col > qrow + fg * 4 + r) p[qb][nt][r] = -INFINITY;
          }
        }
      }

      // ---- defer-max check (T13): lane-local maxes only ----
      float lmax[2][4];
      bool ok = true;
#pragma unroll
      for (int qb = 0; qb < 2; ++qb)
#pragma unroll
        for (int r = 0; r < 4; ++r) {
          lmax[qb][r] = fmaxf(fmaxf(p[qb][0][r], p[qb][1][r]), fmaxf(p[qb][2][r], p[qb][3][r]));
          ok = ok && (lmax[qb][r] <= m_run[qb][r] + 8.0f);
        }
      if (!__all(ok)) {   // rare: first tile per wave + occasional max growth
#pragma unroll
        for (int qb = 0; qb < 2; ++qb)
#pragma unroll
          for (int r = 0; r < 4; ++r) {
            float tm = lmax[qb][r];
#pragma unroll
            for (int off = 1; off < 16; off <<= 1)
              tm = fmaxf(tm, __shfl_xor(tm, off));
            float mn = fmaxf(m_run[qb][r], tm);
            float sc = exp2f(m_run[qb][r] - mn);
            m_run[qb][r] = mn;
            l_part[qb][r] *= sc;
#pragma unroll
            for (int d = 0; d < 4; ++d) acc[qb][d][r] *= sc;
          }
      }

      // ---- P = exp2(S - m), lane-local l partials, packed P-store ----
#pragma unroll
      for (int qb = 0; qb < 2; ++qb)
#pragma unroll
        for (int nt = 0; nt < 4; ++nt) {
          float pv0 = exp2f(p[qb][nt][0] - m_run[qb][0]);
          float pv1 = exp2f(p[qb][nt][1] - m_run[qb][1]);
          float pv2 = exp2f(p[qb][nt][2] - m_run[qb][2]);
          float pv3 = exp2f(p[qb][nt][3] - m_run[qb][3]);
          l_part[qb][0] += pv0;
          l_part[qb][1] += pv1;
          l_part[qb][2] += pv2;
          l_part[qb][3] += pv3;
          PSTORE(pva[qb][nt], pv0, pv1, pv2, pv3);
        }
      asm volatile("s_waitcnt lgkmcnt(0)" ::: "memory");
      __builtin_amdgcn_sched_barrier(0);

      // ---- PV: acc[qb][dblk] += P * V ----
      bf16x8 pa[2][2];
#pragma unroll
      for (int qb = 0; qb < 2; ++qb)
#pragma unroll
        for (int hf = 0; hf < 2; ++hf)
          pa[qb][hf] = *(const bf16x8*)(&PsRaw[wid][qb][0] + fr * 144 +
                                        ((hf * 64 + fg * 16) ^ ((fr >> 2) << 5)));
      const unsigned char* vbuf = &VtRaw[kt & 1][0];
      __builtin_amdgcn_s_setprio(1);
#pragma unroll
      for (int dblk = 0; dblk < 4; ++dblk) {
        int xr = ((fr & 7) ^ ((dblk * 2 + (fr >> 3)) & 7)) << 4;
        const unsigned char* vp = vbuf + (dblk * 16 + fr) * 128;
        bf16x8 b0 = *(const bf16x8*)(vp + ((fg * 16) ^ xr));
        bf16x8 b1 = *(const bf16x8*)(vp + ((64 + fg * 16) ^ xr));
        acc[0][dblk] = __builtin_amdgcn_mfma_f32_16x16x32_bf16(pa[0][0], b0, acc[0][dblk], 0, 0, 0);
        acc[1][dblk] = __builtin_amdgcn_mfma_f32_16x16x32_bf16(pa[1][0], b0, acc[1][dblk], 0, 0, 0);
        acc[0][dblk] = __builtin_amdgcn_mfma_f32_16x16x32_bf16(pa[0][1], b1, acc[0][dblk], 0, 0, 0);
        acc[1][dblk] = __builtin_amdgcn_mfma_f32_16x16x32_bf16(pa[1][1], b1, acc[1][dblk], 0, 0, 0);
      }
      __builtin_amdgcn_s_setprio(0);
    }

    if (hn) STAGE_V_WRITE(nva, nvb, &VtRaw[(kt + 1) & 1][0]);
  }
#undef STAGE_K
#undef STAGE_V_WRITE

  // epilogue: single l-sum tree per (qb,r), then O-write
#pragma unroll
  for (int qb = 0; qb < 2; ++qb)
#pragma unroll
    for (int r = 0; r < 4; ++r) {
      float l = l_part[qb][r];
#pragma unroll
      for (int off = 1; off < 16; off <<= 1)
        l += __shfl_xor(l, off);
      float rl = 1.0f / l;
      int row = qrow0 + qb * 16 + fg * 4 + r;
      unsigned short* orow = O + ((size_t)b * T_SEQ + row) * D_MODEL + h * HD;
#pragma unroll
      for (int d = 0; d < 4; ++d)
        orow[d * 16 + fr] = f2bf(acc[qb][d][r] * rl);
    }
}

// ---------------- launch ----------------
extern "C" void kernel_launch(void* const* d_in, const int* in_sizes, int n_in,
                              void* d_out, int out_size, void* d_ws, size_t ws_size,
                              hipStream_t stream) {
  const float* x   = (const float*)d_in[0];
  const int*   pos = (const int*)d_in[1];
  const float* Wq  = (const float*)d_in[2];
  const float* Wk  = (const float*)d_in[3];
  const float* Wv  = (const float*)d_in[4];
  const float* Wo  = (const float*)d_in[5];

  const size_t M  = (size_t)BATCH * T_SEQ;   // 4096
  const size_t DD = (size_t)D_MODEL * D_MODEL;

  char* ws = (char*)d_ws;
  unsigned short* xb  = (unsigned short*)ws; ws += M * D_MODEL * 2;
  unsigned short* Wqb = (unsigned short*)ws; ws += DD * 2;
  unsigned short* Wkb = (unsigned short*)ws; ws += DD * 2;
  unsigned short* Wvb = (unsigned short*)ws; ws += DD * 2;
  unsigned short* Wob = (unsigned short*)ws; ws += DD * 2;
  unsigned short* Qp  = (unsigned short*)ws; ws += M * D_MODEL * 2;
  unsigned short* Kp  = (unsigned short*)ws; ws += M * D_MODEL * 2;
  unsigned short* Vp  = (unsigned short*)ws; ws += M * D_MODEL * 2;
  unsigned short* Ob  = (unsigned short*)ws; ws += M * D_MODEL * 2;

  // casts
  int n4x = (int)(M * D_MODEL / 4);
  cast_kernel<<<(n4x + 255) / 256, 256, 0, stream>>>(x, xb, n4x);
  cast4_kernel<<<4096, 256, 0, stream>>>(Wq, Wk, Wv, Wo, Wqb, Wkb, Wvb, Wob);

  // fused QKV projection
  gemm_bt<128, false><<<dim3(24, (unsigned)(M / 128)), 256, 0, stream>>>(
      xb, Wqb, Wkb, Wvb, Qp, Kp, Vp, (int)M, D_MODEL);

  // rope on Q,K in place (Q pre-scaled by (1/8)*log2e)
  int total = (int)(M * 512);
  rope_kernel<<<(total + 255) / 256, 256, 0, stream>>>(Qp, Kp, pos, total);

  // attention: 128 q-rows/block, reversed qt for load balance
  attn_kernel<<<dim3(T_SEQ / 128, BATCH * NH), 256, 0, stream>>>(Qp, Kp, Vp, Ob);

  // output projection (fp32 out)
  gemm_bt<64, true><<<dim3(16, (unsigned)(M / 128)), 256, 0, stream>>>(
      Ob, Wob, Wob, Wob, d_out, d_out, d_out, (int)M, D_MODEL);
}

// Round 6
// 141.045 us; speedup vs baseline: 2.2915x; 1.2473x over previous
//
#include <hip/hip_runtime.h>
#include <math.h>
#include <stdint.h>

#define D_MODEL 1024
#define T_SEQ   2048
#define BATCH   2
#define NH      16
#define HD      64

typedef __attribute__((ext_vector_type(8))) short bf16x8;
typedef __attribute__((ext_vector_type(4))) float f32x4;

__device__ inline unsigned short f2bf(float f) {
  union { float f; unsigned int u; } v; v.f = f;
  unsigned int u = v.u;
  unsigned int r = u + 0x7fffu + ((u >> 16) & 1u);
  return (unsigned short)(r >> 16);
}
__device__ inline float bf2f(unsigned short s) {
  union { unsigned int u; float f; } v; v.u = ((unsigned int)s) << 16;
  return v.f;
}

// async global->LDS, 16B per lane, LDS dest = wave-uniform base + lane*16
#define GLDS16(g, l) __builtin_amdgcn_global_load_lds( \
  reinterpret_cast<const __attribute__((address_space(1))) void*>(reinterpret_cast<uintptr_t>(g)), \
  reinterpret_cast<__attribute__((address_space(3))) void*>(reinterpret_cast<uintptr_t>(l)), 16, 0, 0)

// P-quad store: rows r..r+3 at va+{0,144,288,432}; cvt_pk pairs (r0,r1),(r2,r3)
#define PSTORE(va_, p0_, p1_, p2_, p3_) do { \
  unsigned t0_, t1_; \
  asm volatile( \
    "v_cvt_pk_bf16_f32 %0, %3, %4\n\t" \
    "v_cvt_pk_bf16_f32 %1, %5, %6\n\t" \
    "ds_write_b16 %2, %0\n\t" \
    "ds_write_b16_d16_hi %2, %0 offset:144\n\t" \
    "ds_write_b16 %2, %1 offset:288\n\t" \
    "ds_write_b16_d16_hi %2, %1 offset:432" \
    : "=&v"(t0_), "=&v"(t1_) \
    : "v"(va_), "v"(p0_), "v"(p1_), "v"(p2_), "v"(p3_) \
    : "memory"); \
} while (0)

// ---------------- casts fp32 -> bf16 ----------------
__global__ void cast_kernel(const float* __restrict__ in, unsigned short* __restrict__ out, int n4) {
  int id = blockIdx.x * blockDim.x + threadIdx.x;
  if (id >= n4) return;
  float4 v = ((const float4*)in)[id];
  ushort4 o;
  o.x = f2bf(v.x); o.y = f2bf(v.y); o.z = f2bf(v.z); o.w = f2bf(v.w);
  ((ushort4*)out)[id] = o;
}

__global__ void cast4_kernel(const float* __restrict__ s0, const float* __restrict__ s1,
                             const float* __restrict__ s2, const float* __restrict__ s3,
                             unsigned short* __restrict__ d0, unsigned short* __restrict__ d1,
                             unsigned short* __restrict__ d2, unsigned short* __restrict__ d3) {
  int id = blockIdx.x * blockDim.x + threadIdx.x;   // 4 * 2^18
  int m = id >> 18, r = id & ((1 << 18) - 1);
  const float* s = (m == 0) ? s0 : (m == 1) ? s1 : (m == 2) ? s2 : s3;
  unsigned short* dd = (m == 0) ? d0 : (m == 1) ? d1 : (m == 2) ? d2 : d3;
  float4 v = ((const float4*)s)[r];
  ushort4 o;
  o.x = f2bf(v.x); o.y = f2bf(v.y); o.z = f2bf(v.z); o.w = f2bf(v.w);
  ((ushort4*)dd)[r] = o;
}

// ---------------- GEMM: C[M,1024] = A[M,K] * B[1024,K]^T (bf16, fp32 acc) ----------------
template<int BN, bool F32OUT>
__global__ __launch_bounds__(256)
void gemm_bt(const unsigned short* __restrict__ A,
             const unsigned short* __restrict__ B0, const unsigned short* __restrict__ B1,
             const unsigned short* __restrict__ B2,
             void* __restrict__ C0, void* __restrict__ C1, void* __restrict__ C2,
             int M, int K) {
  constexpr int NPM = 1024 / BN;
  constexpr int NWC = BN / 64;
  constexpr int MI  = 2 * NWC;
  __shared__ __align__(16) unsigned short As[128 * 32];
  __shared__ __align__(16) unsigned short Bs[BN * 32];

  const int tid = threadIdx.x, lane = tid & 63, wid = tid >> 6;
  const int wr = wid / NWC, wc = wid % NWC;
  const int bx = blockIdx.x;
  const int mat = bx / NPM;
  const int bn = (bx % NPM) * BN;
  const int bm = blockIdx.y * 128;
  const unsigned short* B = (mat == 0) ? B0 : (mat == 1) ? B1 : B2;
  void* C = (mat == 0) ? C0 : (mat == 1) ? C1 : C2;

  f32x4 acc[MI][4];
#pragma unroll
  for (int i = 0; i < MI; i++)
#pragma unroll
    for (int j = 0; j < 4; j++) acc[i][j] = (f32x4){0.f, 0.f, 0.f, 0.f};

  const int fr = lane & 15, fg = lane >> 4;
  const int lrow = lane >> 2, lcol = (lane & 3) * 8;

  for (int kb = 0; kb < K; kb += 32) {
#pragma unroll
    for (int c = 0; c < 2; ++c) {
      int rb = wid * 32 + c * 16;
      GLDS16(A + (size_t)(bm + rb + lrow) * K + kb + lcol, As + rb * 32);
    }
#pragma unroll
    for (int c = 0; c < BN / 64; ++c) {
      int rb = wid * (BN / 4) + c * 16;
      GLDS16(B + (size_t)(bn + rb + lrow) * K + kb + lcol, Bs + rb * 32);
    }
    __syncthreads();
    bf16x8 a[MI], bq[4];
#pragma unroll
    for (int mi = 0; mi < MI; mi++)
      a[mi] = *(const bf16x8*)&As[(wr * (16 * MI) + mi * 16 + fr) * 32 + fg * 8];
#pragma unroll
    for (int ni = 0; ni < 4; ni++)
      bq[ni] = *(const bf16x8*)&Bs[(wc * 64 + ni * 16 + fr) * 32 + fg * 8];
#pragma unroll
    for (int mi = 0; mi < MI; mi++)
#pragma unroll
      for (int ni = 0; ni < 4; ni++)
        acc[mi][ni] = __builtin_amdgcn_mfma_f32_16x16x32_bf16(a[mi], bq[ni], acc[mi][ni], 0, 0, 0);
    __syncthreads();
  }

  const int fc = lane & 15, fq = lane >> 4;
#pragma unroll
  for (int mi = 0; mi < MI; mi++)
#pragma unroll
    for (int ni = 0; ni < 4; ni++) {
      int col = bn + wc * 64 + ni * 16 + fc;
#pragma unroll
      for (int r = 0; r < 4; r++) {
        int row = bm + wr * (16 * MI) + mi * 16 + fq * 4 + r;
        if (F32OUT) ((float*)C)[(size_t)row * 1024 + col] = acc[mi][ni][r];
        else ((unsigned short*)C)[(size_t)row * 1024 + col] = f2bf(acc[mi][ni][r]);
      }
    }
}

// ---------------- RoPE in-place; Q additionally pre-scaled by (1/8)*log2e ----------------
__global__ void rope_kernel(unsigned short* __restrict__ Qp, unsigned short* __restrict__ Kp,
                            const int* __restrict__ pos, int total) {
  const float SCL = 0.18033688011f;   // (1/8) * log2(e): folds attn scale into Q
  int id = blockIdx.x * blockDim.x + threadIdx.x;
  if (id >= total) return;
  int m  = id >> 9;
  int p2 = id & 511;
  int p  = p2 & 31;
  float posf = (float)pos[m];
  float inv  = powf(10000.0f, (float)(-2 * p) / 64.0f);
  float ang  = posf * inv;
  float sn, cs;
  sincosf(ang, &sn, &cs);
  size_t off = (size_t)m * D_MODEL + 2 * p2;
  float q1 = bf2f(Qp[off]), q2 = bf2f(Qp[off + 1]);
  Qp[off]     = f2bf((q1 * cs - q2 * sn) * SCL);
  Qp[off + 1] = f2bf((q1 * sn + q2 * cs) * SCL);
  float k1 = bf2f(Kp[off]), k2 = bf2f(Kp[off + 1]);
  Kp[off]     = f2bf(k1 * cs - k2 * sn);
  Kp[off + 1] = f2bf(k1 * sn + k2 * cs);
}

// ---------------- Flash attention, causal, bf16 MFMA ----------------
// R5-verified per-unit pipeline (K fragment-major via global_load_lds, Vt
// transposed+swizzled dbuf, Ps 144B-swizzled, defer-max + deferred l-sum,
// cvt_pk P-store, setprio). R6: CAUSAL PAIRING for perfect balance — each
// block owns 64-row q-tiles (i, 31-i): (i+1)+(32-i) = 33 kv-units for EVERY
// block. 512 uniform blocks = exactly 2/CU, no drain tail. 4 waves x 16
// q-rows; two sequential kv-loops share one double-buffered pipeline
// (parity runs across the boundary; B's tile 0 prefetched in A's last unit).
__global__ __launch_bounds__(256, 3)
void attn_kernel(const unsigned short* __restrict__ Q, const unsigned short* __restrict__ K,
                 const unsigned short* __restrict__ V, unsigned short* __restrict__ O) {
  __shared__ __align__(16) unsigned char KsRaw[2][8192];   // [buf][idx=nt*2+half][lane][16B]
  __shared__ __align__(16) unsigned char VtRaw[2][8192];   // [buf][d][128B swizzled row]
  __shared__ __align__(16) unsigned char PsRaw[4][2304];   // [wave][row*144 swizzled]

  const int bh = blockIdx.y;
  const int b  = bh >> 4, h = bh & 15;
  const int pr = blockIdx.x;                 // pair index 0..15
  const int tid = threadIdx.x, lane = tid & 63, wid = tid >> 6;
  const int fr = lane & 15, fg = lane >> 4;

  const size_t base = ((size_t)b * T_SEQ) * D_MODEL + h * HD;
  const unsigned short* Qb = Q + base;
  const unsigned short* Kb = K + base;
  const unsigned short* Vb = V + base;

  const int qt0 = pr, qt1 = 31 - pr;         // paired 64-row q-tiles
  const int ntkA = pr + 1;                   // kv-tiles for phase A
  const int ntkB = 32 - pr;                  // kv-tiles for phase B

  // Q frags for both tiles (pre-scaled in rope): Q[qt*64 + wid*16 + fr][fg*8 + j]
  bf16x8 qfA0, qfA1, qfB0, qfB1;
  {
    const unsigned short* qp0 = Qb + (size_t)(qt0 * 64 + wid * 16 + fr) * D_MODEL + fg * 8;
    qfA0 = *(const bf16x8*)qp0;  qfA1 = *(const bf16x8*)(qp0 + 32);
    const unsigned short* qp1 = Qb + (size_t)(qt1 * 64 + wid * 16 + fr) * D_MODEL + fg * 8;
    qfB0 = *(const bf16x8*)qp1;  qfB1 = *(const bf16x8*)(qp1 + 32);
  }

  // V staging: thread -> kv-pair sg (0..31), d-range sd0..sd0+7
  const int sg  = tid >> 3;
  const int sd0 = (tid & 7) * 8;
  const int sx  = tid & 7;

#define STAGE_K(kvbase, buf) do { \
    _Pragma("unroll") \
    for (int c_ = 0; c_ < 2; ++c_) { \
      int idx_ = wid * 2 + c_; \
      int nt_ = idx_ >> 1, hf_ = idx_ & 1; \
      GLDS16(Kb + (size_t)((kvbase) + nt_ * 16 + fr) * D_MODEL + hf_ * 32 + fg * 8, \
             &KsRaw[buf][idx_ * 1024]); \
    } \
  } while (0)

#define STAGE_V_WRITE(ra_, rb_, bufp_) do { \
    _Pragma("unroll") \
    for (int j_ = 0; j_ < 8; ++j_) { \
      unsigned pk_ = (unsigned)(unsigned short)(ra_)[j_] | ((unsigned)(unsigned short)(rb_)[j_] << 16); \
      *(unsigned*)((bufp_) + (sd0 + j_) * 128 + ((sg * 4) ^ ((j_ ^ sx) << 4))) = pk_; \
    } \
  } while (0)

  // prologue: stage K tile 0 (async) + V tile 0 into buf 0
  STAGE_K(0, 0);
  {
    bf16x8 ra = *(const bf16x8*)(Vb + (size_t)(2 * sg    ) * D_MODEL + sd0);
    bf16x8 rb = *(const bf16x8*)(Vb + (size_t)(2 * sg + 1) * D_MODEL + sd0);
    STAGE_V_WRITE(ra, rb, &VtRaw[0][0]);
  }

  // precomputed P-store addresses: PsRaw[wid] + fg*576 + ((nt*32+fr*2)^(fg<<5))
  unsigned pva[4];
  {
    unsigned psb = (unsigned)(uintptr_t)(void*)&PsRaw[wid][0];
#pragma unroll
    for (int nt = 0; nt < 4; ++nt)
      pva[nt] = psb + fg * 576 + (unsigned)((nt * 32 + fr * 2) ^ (fg << 5));
  }

  float m_run[4], l_part[4];
  f32x4 acc[4];
#pragma unroll
  for (int r = 0; r < 4; ++r) { m_run[r] = -INFINITY; l_part[r] = 0.f; }
#pragma unroll
  for (int d = 0; d < 4; ++d) acc[d] = (f32x4){0.f, 0.f, 0.f, 0.f};

  // one kv-unit: compute on buf `par`, prefetch kvn into buf par^1 (if hn)
#define UNIT(qt_, kt_, qlo_, qhi_, par_, hn_, kvn_) do { \
    __syncthreads(); \
    bf16x8 nva, nvb; \
    if (hn_) { \
      STAGE_K(kvn_, (par_) ^ 1); \
      nva = *(const bf16x8*)(Vb + (size_t)((kvn_) + 2 * sg    ) * D_MODEL + sd0); \
      nvb = *(const bf16x8*)(Vb + (size_t)((kvn_) + 2 * sg + 1) * D_MODEL + sd0); \
    } \
    const unsigned char* kbuf = &KsRaw[par_][0]; \
    f32x4 st[4]; \
    __builtin_amdgcn_s_setprio(1); \
    _Pragma("unroll") \
    for (int nt = 0; nt < 4; ++nt) { \
      bf16x8 kf0 = *(const bf16x8*)(kbuf + (nt * 2    ) * 1024 + lane * 16); \
      bf16x8 kf1 = *(const bf16x8*)(kbuf + (nt * 2 + 1) * 1024 + lane * 16); \
      f32x4 sa = (f32x4){0.f, 0.f, 0.f, 0.f}; \
      sa = __builtin_amdgcn_mfma_f32_16x16x32_bf16(qlo_, kf0, sa, 0, 0, 0); \
      sa = __builtin_amdgcn_mfma_f32_16x16x32_bf16(qhi_, kf1, sa, 0, 0, 0); \
      st[nt] = sa; \
    } \
    __builtin_amdgcn_s_setprio(0); \
    float p[4][4]; \
    _Pragma("unroll") \
    for (int nt = 0; nt < 4; ++nt) \
      _Pragma("unroll") \
      for (int r = 0; r < 4; ++r) p[nt][r] = st[nt][r]; \
    if ((kt_) == (qt_)) {   /* diagonal tile: mask cols > row */ \
      _Pragma("unroll") \
      for (int nt = 0; nt < 4; ++nt) { \
        _Pragma("unroll") \
        for (int r = 0; r < 4; ++r) \
          if (nt * 16 + fr > wid * 16 + fg * 4 + r) p[nt][r] = -INFINITY; \
      } \
    } \
    float lmax[4]; \
    bool ok = true; \
    _Pragma("unroll") \
    for (int r = 0; r < 4; ++r) { \
      lmax[r] = fmaxf(fmaxf(p[0][r], p[1][r]), fmaxf(p[2][r], p[3][r])); \
      ok = ok && (lmax[r] <= m_run[r] + 8.0f); \
    } \
    if (!__all(ok)) { \
      _Pragma("unroll") \
      for (int r = 0; r < 4; ++r) { \
        float tm = lmax[r]; \
        tm = fmaxf(tm, __shfl_xor(tm, 1)); \
        tm = fmaxf(tm, __shfl_xor(tm, 2)); \
        tm = fmaxf(tm, __shfl_xor(tm, 4)); \
        tm = fmaxf(tm, __shfl_xor(tm, 8)); \
        float mn = fmaxf(m_run[r], tm); \
        float sc = exp2f(m_run[r] - mn); \
        m_run[r] = mn; \
        l_part[r] *= sc; \
        _Pragma("unroll") \
        for (int d = 0; d < 4; ++d) acc[d][r] *= sc; \
      } \
    } \
    _Pragma("unroll") \
    for (int nt = 0; nt < 4; ++nt) { \
      float pv0 = exp2f(p[nt][0] - m_run[0]); \
      float pv1 = exp2f(p[nt][1] - m_run[1]); \
      float pv2 = exp2f(p[nt][2] - m_run[2]); \
      float pv3 = exp2f(p[nt][3] - m_run[3]); \
      l_part[0] += pv0; l_part[1] += pv1; l_part[2] += pv2; l_part[3] += pv3; \
      PSTORE(pva[nt], pv0, pv1, pv2, pv3); \
    } \
    asm volatile("s_waitcnt lgkmcnt(0)" ::: "memory"); \
    __builtin_amdgcn_sched_barrier(0); \
    bf16x8 pa0 = *(const bf16x8*)(&PsRaw[wid][0] + fr * 144 + ((     fg * 16) ^ ((fr >> 2) << 5))); \
    bf16x8 pa1 = *(const bf16x8*)(&PsRaw[wid][0] + fr * 144 + ((64 + fg * 16) ^ ((fr >> 2) << 5))); \
    const unsigned char* vbuf = &VtRaw[par_][0]; \
    __builtin_amdgcn_s_setprio(1); \
    _Pragma("unroll") \
    for (int dblk = 0; dblk < 4; ++dblk) { \
      int xr = ((fr & 7) ^ ((dblk * 2 + (fr >> 3)) & 7)) << 4; \
      const unsigned char* vp = vbuf + (dblk * 16 + fr) * 128; \
      bf16x8 b0 = *(const bf16x8*)(vp + ((fg * 16) ^ xr)); \
      bf16x8 b1 = *(const bf16x8*)(vp + ((64 + fg * 16) ^ xr)); \
      acc[dblk] = __builtin_amdgcn_mfma_f32_16x16x32_bf16(pa0, b0, acc[dblk], 0, 0, 0); \
      acc[dblk] = __builtin_amdgcn_mfma_f32_16x16x32_bf16(pa1, b1, acc[dblk], 0, 0, 0); \
    } \
    __builtin_amdgcn_s_setprio(0); \
    if (hn_) STAGE_V_WRITE(nva, nvb, &VtRaw[(par_) ^ 1][0]); \
  } while (0)

#define EPILOGUE(qt_) do { \
    _Pragma("unroll") \
    for (int r = 0; r < 4; ++r) { \
      float l = l_part[r]; \
      l += __shfl_xor(l, 1); l += __shfl_xor(l, 2); \
      l += __shfl_xor(l, 4); l += __shfl_xor(l, 8); \
      float rl = 1.0f / l; \
      int row = (qt_) * 64 + wid * 16 + fg * 4 + r; \
      unsigned short* orow = O + ((size_t)b * T_SEQ + row) * D_MODEL + h * HD; \
      _Pragma("unroll") \
      for (int d = 0; d < 4; ++d) orow[d * 16 + fr] = f2bf(acc[d][r] * rl); \
    } \
  } while (0)

  int par = 0;
  // ---- phase A: q-tile qt0, kv-tiles 0..ntkA-1 (B always follows: hn true) ----
  for (int kt = 0; kt < ntkA; ++kt) {
    int kvn = (kt + 1 < ntkA) ? (kt + 1) * 64 : 0;   // boundary: prefetch B's kv=0
    UNIT(qt0, kt, qfA0, qfA1, par, true, kvn);
    par ^= 1;
  }
  EPILOGUE(qt0);
#pragma unroll
  for (int r = 0; r < 4; ++r) { m_run[r] = -INFINITY; l_part[r] = 0.f; }
#pragma unroll
  for (int d = 0; d < 4; ++d) acc[d] = (f32x4){0.f, 0.f, 0.f, 0.f};
  // ---- phase B: q-tile qt1, kv-tiles 0..ntkB-1 ----
  for (int kt = 0; kt < ntkB; ++kt) {
    bool hn = (kt + 1 < ntkB);
    int kvn = (kt + 1) * 64;
    UNIT(qt1, kt, qfB0, qfB1, par, hn, kvn);
    par ^= 1;
  }
  EPILOGUE(qt1);
#undef UNIT
#undef EPILOGUE
#undef STAGE_K
#undef STAGE_V_WRITE
}

// ---------------- launch ----------------
extern "C" void kernel_launch(void* const* d_in, const int* in_sizes, int n_in,
                              void* d_out, int out_size, void* d_ws, size_t ws_size,
                              hipStream_t stream) {
  const float* x   = (const float*)d_in[0];
  const int*   pos = (const int*)d_in[1];
  const float* Wq  = (const float*)d_in[2];
  const float* Wk  = (const float*)d_in[3];
  const float* Wv  = (const float*)d_in[4];
  const float* Wo  = (const float*)d_in[5];

  const size_t M  = (size_t)BATCH * T_SEQ;   // 4096
  const size_t DD = (size_t)D_MODEL * D_MODEL;

  char* ws = (char*)d_ws;
  unsigned short* xb  = (unsigned short*)ws; ws += M * D_MODEL * 2;
  unsigned short* Wqb = (unsigned short*)ws; ws += DD * 2;
  unsigned short* Wkb = (unsigned short*)ws; ws += DD * 2;
  unsigned short* Wvb = (unsigned short*)ws; ws += DD * 2;
  unsigned short* Wob = (unsigned short*)ws; ws += DD * 2;
  unsigned short* Qp  = (unsigned short*)ws; ws += M * D_MODEL * 2;
  unsigned short* Kp  = (unsigned short*)ws; ws += M * D_MODEL * 2;
  unsigned short* Vp  = (unsigned short*)ws; ws += M * D_MODEL * 2;
  unsigned short* Ob  = (unsigned short*)ws; ws += M * D_MODEL * 2;

  // casts
  int n4x = (int)(M * D_MODEL / 4);
  cast_kernel<<<(n4x + 255) / 256, 256, 0, stream>>>(x, xb, n4x);
  cast4_kernel<<<4096, 256, 0, stream>>>(Wq, Wk, Wv, Wo, Wqb, Wkb, Wvb, Wob);

  // fused QKV projection
  gemm_bt<128, false><<<dim3(24, (unsigned)(M / 128)), 256, 0, stream>>>(
      xb, Wqb, Wkb, Wvb, Qp, Kp, Vp, (int)M, D_MODEL);

  // rope on Q,K in place (Q pre-scaled by (1/8)*log2e)
  int total = (int)(M * 512);
  rope_kernel<<<(total + 255) / 256, 256, 0, stream>>>(Qp, Kp, pos, total);

  // attention: paired q-tiles (i, 31-i) -> 512 uniform blocks of 33 kv-units
  attn_kernel<<<dim3(16, BATCH * NH), 256, 0, stream>>>(Qp, Kp, Vp, Ob);

  // output projection (fp32 out)
  gemm_bt<64, true><<<dim3(16, (unsigned)(M / 128)), 256, 0, stream>>>(
      Ob, Wob, Wob, Wob, d_out, d_out, d_out, (int)M, D_MODEL);
}

// Round 7
// 130.128 us; speedup vs baseline: 2.4837x; 1.0839x over previous
//
#include <hip/hip_runtime.h>
#include <math.h>
#include <stdint.h>

#define D_MODEL 1024
#define T_SEQ   2048
#define BATCH   2
#define NH      16
#define HD      64

typedef __attribute__((ext_vector_type(8))) short bf16x8;
typedef __attribute__((ext_vector_type(4))) float f32x4;

__device__ inline unsigned short f2bf(float f) {
  union { float f; unsigned int u; } v; v.f = f;
  unsigned int u = v.u;
  unsigned int r = u + 0x7fffu + ((u >> 16) & 1u);
  return (unsigned short)(r >> 16);
}
__device__ inline float bf2f(unsigned short s) {
  union { unsigned int u; float f; } v; v.u = ((unsigned int)s) << 16;
  return v.f;
}

// async global->LDS, 16B per lane, LDS dest = wave-uniform base + lane*16
#define GLDS16(g, l) __builtin_amdgcn_global_load_lds( \
  reinterpret_cast<const __attribute__((address_space(1))) void*>(reinterpret_cast<uintptr_t>(g)), \
  reinterpret_cast<__attribute__((address_space(3))) void*>(reinterpret_cast<uintptr_t>(l)), 16, 0, 0)

// P-quad store: rows r..r+3 at va+{0,144,288,432}; cvt_pk pairs (r0,r1),(r2,r3)
#define PSTORE(va_, p0_, p1_, p2_, p3_) do { \
  unsigned t0_, t1_; \
  asm volatile( \
    "v_cvt_pk_bf16_f32 %0, %3, %4\n\t" \
    "v_cvt_pk_bf16_f32 %1, %5, %6\n\t" \
    "ds_write_b16 %2, %0\n\t" \
    "ds_write_b16_d16_hi %2, %0 offset:144\n\t" \
    "ds_write_b16 %2, %1 offset:288\n\t" \
    "ds_write_b16_d16_hi %2, %1 offset:432" \
    : "=&v"(t0_), "=&v"(t1_) \
    : "v"(va_), "v"(p0_), "v"(p1_), "v"(p2_), "v"(p3_) \
    : "memory"); \
} while (0)

// ---------------- casts fp32 -> bf16 ----------------
__global__ void cast_kernel(const float* __restrict__ in, unsigned short* __restrict__ out, int n4) {
  int id = blockIdx.x * blockDim.x + threadIdx.x;
  if (id >= n4) return;
  float4 v = ((const float4*)in)[id];
  ushort4 o;
  o.x = f2bf(v.x); o.y = f2bf(v.y); o.z = f2bf(v.z); o.w = f2bf(v.w);
  ((ushort4*)out)[id] = o;
}

__global__ void cast4_kernel(const float* __restrict__ s0, const float* __restrict__ s1,
                             const float* __restrict__ s2, const float* __restrict__ s3,
                             unsigned short* __restrict__ d0, unsigned short* __restrict__ d1,
                             unsigned short* __restrict__ d2, unsigned short* __restrict__ d3) {
  int id = blockIdx.x * blockDim.x + threadIdx.x;   // 4 * 2^18
  int m = id >> 18, r = id & ((1 << 18) - 1);
  const float* s = (m == 0) ? s0 : (m == 1) ? s1 : (m == 2) ? s2 : s3;
  unsigned short* dd = (m == 0) ? d0 : (m == 1) ? d1 : (m == 2) ? d2 : d3;
  float4 v = ((const float4*)s)[r];
  ushort4 o;
  o.x = f2bf(v.x); o.y = f2bf(v.y); o.z = f2bf(v.z); o.w = f2bf(v.w);
  ((ushort4*)dd)[r] = o;
}

// ---------------- GEMM: C[M,1024] = A[M,K] * B[1024,K]^T (bf16, fp32 acc) ----------------
template<int BN, bool F32OUT>
__global__ __launch_bounds__(256)
void gemm_bt(const unsigned short* __restrict__ A,
             const unsigned short* __restrict__ B0, const unsigned short* __restrict__ B1,
             const unsigned short* __restrict__ B2,
             void* __restrict__ C0, void* __restrict__ C1, void* __restrict__ C2,
             int M, int K) {
  constexpr int NPM = 1024 / BN;
  constexpr int NWC = BN / 64;
  constexpr int MI  = 2 * NWC;
  __shared__ __align__(16) unsigned short As[128 * 32];
  __shared__ __align__(16) unsigned short Bs[BN * 32];

  const int tid = threadIdx.x, lane = tid & 63, wid = tid >> 6;
  const int wr = wid / NWC, wc = wid % NWC;
  const int bx = blockIdx.x;
  const int mat = bx / NPM;
  const int bn = (bx % NPM) * BN;
  const int bm = blockIdx.y * 128;
  const unsigned short* B = (mat == 0) ? B0 : (mat == 1) ? B1 : B2;
  void* C = (mat == 0) ? C0 : (mat == 1) ? C1 : C2;

  f32x4 acc[MI][4];
#pragma unroll
  for (int i = 0; i < MI; i++)
#pragma unroll
    for (int j = 0; j < 4; j++) acc[i][j] = (f32x4){0.f, 0.f, 0.f, 0.f};

  const int fr = lane & 15, fg = lane >> 4;
  const int lrow = lane >> 2, lcol = (lane & 3) * 8;

  for (int kb = 0; kb < K; kb += 32) {
#pragma unroll
    for (int c = 0; c < 2; ++c) {
      int rb = wid * 32 + c * 16;
      GLDS16(A + (size_t)(bm + rb + lrow) * K + kb + lcol, As + rb * 32);
    }
#pragma unroll
    for (int c = 0; c < BN / 64; ++c) {
      int rb = wid * (BN / 4) + c * 16;
      GLDS16(B + (size_t)(bn + rb + lrow) * K + kb + lcol, Bs + rb * 32);
    }
    __syncthreads();
    bf16x8 a[MI], bq[4];
#pragma unroll
    for (int mi = 0; mi < MI; mi++)
      a[mi] = *(const bf16x8*)&As[(wr * (16 * MI) + mi * 16 + fr) * 32 + fg * 8];
#pragma unroll
    for (int ni = 0; ni < 4; ni++)
      bq[ni] = *(const bf16x8*)&Bs[(wc * 64 + ni * 16 + fr) * 32 + fg * 8];
#pragma unroll
    for (int mi = 0; mi < MI; mi++)
#pragma unroll
      for (int ni = 0; ni < 4; ni++)
        acc[mi][ni] = __builtin_amdgcn_mfma_f32_16x16x32_bf16(a[mi], bq[ni], acc[mi][ni], 0, 0, 0);
    __syncthreads();
  }

  const int fc = lane & 15, fq = lane >> 4;
#pragma unroll
  for (int mi = 0; mi < MI; mi++)
#pragma unroll
    for (int ni = 0; ni < 4; ni++) {
      int col = bn + wc * 64 + ni * 16 + fc;
#pragma unroll
      for (int r = 0; r < 4; r++) {
        int row = bm + wr * (16 * MI) + mi * 16 + fq * 4 + r;
        if (F32OUT) ((float*)C)[(size_t)row * 1024 + col] = acc[mi][ni][r];
        else ((unsigned short*)C)[(size_t)row * 1024 + col] = f2bf(acc[mi][ni][r]);
      }
    }
}

// ---------------- RoPE in-place; Q additionally pre-scaled by (1/8)*log2e ----------------
__global__ void rope_kernel(unsigned short* __restrict__ Qp, unsigned short* __restrict__ Kp,
                            const int* __restrict__ pos, int total) {
  const float SCL = 0.18033688011f;   // (1/8) * log2(e): folds attn scale into Q
  int id = blockIdx.x * blockDim.x + threadIdx.x;
  if (id >= total) return;
  int m  = id >> 9;
  int p2 = id & 511;
  int p  = p2 & 31;
  float posf = (float)pos[m];
  float inv  = powf(10000.0f, (float)(-2 * p) / 64.0f);
  float ang  = posf * inv;
  float sn, cs;
  sincosf(ang, &sn, &cs);
  size_t off = (size_t)m * D_MODEL + 2 * p2;
  float q1 = bf2f(Qp[off]), q2 = bf2f(Qp[off + 1]);
  Qp[off]     = f2bf((q1 * cs - q2 * sn) * SCL);
  Qp[off + 1] = f2bf((q1 * sn + q2 * cs) * SCL);
  float k1 = bf2f(Kp[off]), k2 = bf2f(Kp[off + 1]);
  Kp[off]     = f2bf(k1 * cs - k2 * sn);
  Kp[off + 1] = f2bf(k1 * sn + k2 * cs);
}

// ---------------- Flash attention, causal, bf16 MFMA ----------------
// R6 structure (causal pairing: block owns q-tiles (i,31-i) = uniform 33
// kv-units; K fragment-major via global_load_lds; Vt transposed+swizzled
// dbuf; Ps 144B-swizzled; defer-max + deferred l-sum; cvt_pk P-store;
// setprio). R7: (a) XCD-aware block remap — bh's low 3 bits == lin%8, so
// each XCD serves only 4 heads and K/V (2MB) fits its private L2 (FETCH
// was 118MB = 7x compulsory); (b) __builtin_amdgcn_exp2f (raw v_exp_f32)
// instead of libm exp2f — 32 calls/lane/unit were the largest VALU term.
__global__ __launch_bounds__(256, 3)
void attn_kernel(const unsigned short* __restrict__ Q, const unsigned short* __restrict__ K,
                 const unsigned short* __restrict__ V, unsigned short* __restrict__ O) {
  __shared__ __align__(16) unsigned char KsRaw[2][8192];   // [buf][idx=nt*2+half][lane][16B]
  __shared__ __align__(16) unsigned char VtRaw[2][8192];   // [buf][d][128B swizzled row]
  __shared__ __align__(16) unsigned char PsRaw[4][2304];   // [wave][row*144 swizzled]

  // XCD-aware decode: xcd = lin%8 (empirical round-robin); bh low bits = xcd
  const int lin  = (int)blockIdx.x;          // 0..511
  const int xcd  = lin & 7;
  const int slot = lin >> 3;                 // 0..63
  const int pr   = slot & 15;                // pair index 0..15
  const int bh   = ((slot >> 4) << 3) | xcd; // 0..31, 4 heads per XCD
  const int b  = bh >> 4, h = bh & 15;
  const int tid = threadIdx.x, lane = tid & 63, wid = tid >> 6;
  const int fr = lane & 15, fg = lane >> 4;

  const size_t base = ((size_t)b * T_SEQ) * D_MODEL + h * HD;
  const unsigned short* Qb = Q + base;
  const unsigned short* Kb = K + base;
  const unsigned short* Vb = V + base;

  const int qt0 = pr, qt1 = 31 - pr;         // paired 64-row q-tiles
  const int ntkA = pr + 1;                   // kv-tiles for phase A
  const int ntkB = 32 - pr;                  // kv-tiles for phase B

  // Q frags for both tiles (pre-scaled in rope): Q[qt*64 + wid*16 + fr][fg*8 + j]
  bf16x8 qfA0, qfA1, qfB0, qfB1;
  {
    const unsigned short* qp0 = Qb + (size_t)(qt0 * 64 + wid * 16 + fr) * D_MODEL + fg * 8;
    qfA0 = *(const bf16x8*)qp0;  qfA1 = *(const bf16x8*)(qp0 + 32);
    const unsigned short* qp1 = Qb + (size_t)(qt1 * 64 + wid * 16 + fr) * D_MODEL + fg * 8;
    qfB0 = *(const bf16x8*)qp1;  qfB1 = *(const bf16x8*)(qp1 + 32);
  }

  // V staging: thread -> kv-pair sg (0..31), d-range sd0..sd0+7
  const int sg  = tid >> 3;
  const int sd0 = (tid & 7) * 8;
  const int sx  = tid & 7;

#define STAGE_K(kvbase, buf) do { \
    _Pragma("unroll") \
    for (int c_ = 0; c_ < 2; ++c_) { \
      int idx_ = wid * 2 + c_; \
      int nt_ = idx_ >> 1, hf_ = idx_ & 1; \
      GLDS16(Kb + (size_t)((kvbase) + nt_ * 16 + fr) * D_MODEL + hf_ * 32 + fg * 8, \
             &KsRaw[buf][idx_ * 1024]); \
    } \
  } while (0)

#define STAGE_V_WRITE(ra_, rb_, bufp_) do { \
    _Pragma("unroll") \
    for (int j_ = 0; j_ < 8; ++j_) { \
      unsigned pk_ = (unsigned)(unsigned short)(ra_)[j_] | ((unsigned)(unsigned short)(rb_)[j_] << 16); \
      *(unsigned*)((bufp_) + (sd0 + j_) * 128 + ((sg * 4) ^ ((j_ ^ sx) << 4))) = pk_; \
    } \
  } while (0)

  // prologue: stage K tile 0 (async) + V tile 0 into buf 0
  STAGE_K(0, 0);
  {
    bf16x8 ra = *(const bf16x8*)(Vb + (size_t)(2 * sg    ) * D_MODEL + sd0);
    bf16x8 rb = *(const bf16x8*)(Vb + (size_t)(2 * sg + 1) * D_MODEL + sd0);
    STAGE_V_WRITE(ra, rb, &VtRaw[0][0]);
  }

  // precomputed P-store addresses: PsRaw[wid] + fg*576 + ((nt*32+fr*2)^(fg<<5))
  unsigned pva[4];
  {
    unsigned psb = (unsigned)(uintptr_t)(void*)&PsRaw[wid][0];
#pragma unroll
    for (int nt = 0; nt < 4; ++nt)
      pva[nt] = psb + fg * 576 + (unsigned)((nt * 32 + fr * 2) ^ (fg << 5));
  }

  float m_run[4], l_part[4];
  f32x4 acc[4];
#pragma unroll
  for (int r = 0; r < 4; ++r) { m_run[r] = -INFINITY; l_part[r] = 0.f; }
#pragma unroll
  for (int d = 0; d < 4; ++d) acc[d] = (f32x4){0.f, 0.f, 0.f, 0.f};

  // one kv-unit: compute on buf `par`, prefetch kvn into buf par^1 (if hn)
#define UNIT(qt_, kt_, qlo_, qhi_, par_, hn_, kvn_) do { \
    __syncthreads(); \
    bf16x8 nva, nvb; \
    if (hn_) { \
      STAGE_K(kvn_, (par_) ^ 1); \
      nva = *(const bf16x8*)(Vb + (size_t)((kvn_) + 2 * sg    ) * D_MODEL + sd0); \
      nvb = *(const bf16x8*)(Vb + (size_t)((kvn_) + 2 * sg + 1) * D_MODEL + sd0); \
    } \
    const unsigned char* kbuf = &KsRaw[par_][0]; \
    f32x4 st[4]; \
    __builtin_amdgcn_s_setprio(1); \
    _Pragma("unroll") \
    for (int nt = 0; nt < 4; ++nt) { \
      bf16x8 kf0 = *(const bf16x8*)(kbuf + (nt * 2    ) * 1024 + lane * 16); \
      bf16x8 kf1 = *(const bf16x8*)(kbuf + (nt * 2 + 1) * 1024 + lane * 16); \
      f32x4 sa = (f32x4){0.f, 0.f, 0.f, 0.f}; \
      sa = __builtin_amdgcn_mfma_f32_16x16x32_bf16(qlo_, kf0, sa, 0, 0, 0); \
      sa = __builtin_amdgcn_mfma_f32_16x16x32_bf16(qhi_, kf1, sa, 0, 0, 0); \
      st[nt] = sa; \
    } \
    __builtin_amdgcn_s_setprio(0); \
    float p[4][4]; \
    _Pragma("unroll") \
    for (int nt = 0; nt < 4; ++nt) \
      _Pragma("unroll") \
      for (int r = 0; r < 4; ++r) p[nt][r] = st[nt][r]; \
    if ((kt_) == (qt_)) {   /* diagonal tile: mask cols > row */ \
      _Pragma("unroll") \
      for (int nt = 0; nt < 4; ++nt) { \
        _Pragma("unroll") \
        for (int r = 0; r < 4; ++r) \
          if (nt * 16 + fr > wid * 16 + fg * 4 + r) p[nt][r] = -INFINITY; \
      } \
    } \
    float lmax[4]; \
    bool ok = true; \
    _Pragma("unroll") \
    for (int r = 0; r < 4; ++r) { \
      lmax[r] = fmaxf(fmaxf(p[0][r], p[1][r]), fmaxf(p[2][r], p[3][r])); \
      ok = ok && (lmax[r] <= m_run[r] + 8.0f); \
    } \
    if (!__all(ok)) { \
      _Pragma("unroll") \
      for (int r = 0; r < 4; ++r) { \
        float tm = lmax[r]; \
        tm = fmaxf(tm, __shfl_xor(tm, 1)); \
        tm = fmaxf(tm, __shfl_xor(tm, 2)); \
        tm = fmaxf(tm, __shfl_xor(tm, 4)); \
        tm = fmaxf(tm, __shfl_xor(tm, 8)); \
        float mn = fmaxf(m_run[r], tm); \
        float sc = __builtin_amdgcn_exp2f(m_run[r] - mn); \
        m_run[r] = mn; \
        l_part[r] *= sc; \
        _Pragma("unroll") \
        for (int d = 0; d < 4; ++d) acc[d][r] *= sc; \
      } \
    } \
    _Pragma("unroll") \
    for (int nt = 0; nt < 4; ++nt) { \
      float pv0 = __builtin_amdgcn_exp2f(p[nt][0] - m_run[0]); \
      float pv1 = __builtin_amdgcn_exp2f(p[nt][1] - m_run[1]); \
      float pv2 = __builtin_amdgcn_exp2f(p[nt][2] - m_run[2]); \
      float pv3 = __builtin_amdgcn_exp2f(p[nt][3] - m_run[3]); \
      l_part[0] += pv0; l_part[1] += pv1; l_part[2] += pv2; l_part[3] += pv3; \
      PSTORE(pva[nt], pv0, pv1, pv2, pv3); \
    } \
    asm volatile("s_waitcnt lgkmcnt(0)" ::: "memory"); \
    __builtin_amdgcn_sched_barrier(0); \
    bf16x8 pa0 = *(const bf16x8*)(&PsRaw[wid][0] + fr * 144 + ((     fg * 16) ^ ((fr >> 2) << 5))); \
    bf16x8 pa1 = *(const bf16x8*)(&PsRaw[wid][0] + fr * 144 + ((64 + fg * 16) ^ ((fr >> 2) << 5))); \
    const unsigned char* vbuf = &VtRaw[par_][0]; \
    __builtin_amdgcn_s_setprio(1); \
    _Pragma("unroll") \
    for (int dblk = 0; dblk < 4; ++dblk) { \
      int xr = ((fr & 7) ^ ((dblk * 2 + (fr >> 3)) & 7)) << 4; \
      const unsigned char* vp = vbuf + (dblk * 16 + fr) * 128; \
      bf16x8 b0 = *(const bf16x8*)(vp + ((fg * 16) ^ xr)); \
      bf16x8 b1 = *(const bf16x8*)(vp + ((64 + fg * 16) ^ xr)); \
      acc[dblk] = __builtin_amdgcn_mfma_f32_16x16x32_bf16(pa0, b0, acc[dblk], 0, 0, 0); \
      acc[dblk] = __builtin_amdgcn_mfma_f32_16x16x32_bf16(pa1, b1, acc[dblk], 0, 0, 0); \
    } \
    __builtin_amdgcn_s_setprio(0); \
    if (hn_) STAGE_V_WRITE(nva, nvb, &VtRaw[(par_) ^ 1][0]); \
  } while (0)

#define EPILOGUE(qt_) do { \
    _Pragma("unroll") \
    for (int r = 0; r < 4; ++r) { \
      float l = l_part[r]; \
      l += __shfl_xor(l, 1); l += __shfl_xor(l, 2); \
      l += __shfl_xor(l, 4); l += __shfl_xor(l, 8); \
      float rl = __builtin_amdgcn_rcpf(l); \
      int row = (qt_) * 64 + wid * 16 + fg * 4 + r; \
      unsigned short* orow = O + ((size_t)b * T_SEQ + row) * D_MODEL + h * HD; \
      _Pragma("unroll") \
      for (int d = 0; d < 4; ++d) orow[d * 16 + fr] = f2bf(acc[d][r] * rl); \
    } \
  } while (0)

  int par = 0;
  // ---- phase A: q-tile qt0, kv-tiles 0..ntkA-1 (B always follows: hn true) ----
  for (int kt = 0; kt < ntkA; ++kt) {
    int kvn = (kt + 1 < ntkA) ? (kt + 1) * 64 : 0;   // boundary: prefetch B's kv=0
    UNIT(qt0, kt, qfA0, qfA1, par, true, kvn);
    par ^= 1;
  }
  EPILOGUE(qt0);
#pragma unroll
  for (int r = 0; r < 4; ++r) { m_run[r] = -INFINITY; l_part[r] = 0.f; }
#pragma unroll
  for (int d = 0; d < 4; ++d) acc[d] = (f32x4){0.f, 0.f, 0.f, 0.f};
  // ---- phase B: q-tile qt1, kv-tiles 0..ntkB-1 ----
  for (int kt = 0; kt < ntkB; ++kt) {
    bool hn = (kt + 1 < ntkB);
    int kvn = (kt + 1) * 64;
    UNIT(qt1, kt, qfB0, qfB1, par, hn, kvn);
    par ^= 1;
  }
  EPILOGUE(qt1);
#undef UNIT
#undef EPILOGUE
#undef STAGE_K
#undef STAGE_V_WRITE
}

// ---------------- launch ----------------
extern "C" void kernel_launch(void* const* d_in, const int* in_sizes, int n_in,
                              void* d_out, int out_size, void* d_ws, size_t ws_size,
                              hipStream_t stream) {
  const float* x   = (const float*)d_in[0];
  const int*   pos = (const int*)d_in[1];
  const float* Wq  = (const float*)d_in[2];
  const float* Wk  = (const float*)d_in[3];
  const float* Wv  = (const float*)d_in[4];
  const float* Wo  = (const float*)d_in[5];

  const size_t M  = (size_t)BATCH * T_SEQ;   // 4096
  const size_t DD = (size_t)D_MODEL * D_MODEL;

  char* ws = (char*)d_ws;
  unsigned short* xb  = (unsigned short*)ws; ws += M * D_MODEL * 2;
  unsigned short* Wqb = (unsigned short*)ws; ws += DD * 2;
  unsigned short* Wkb = (unsigned short*)ws; ws += DD * 2;
  unsigned short* Wvb = (unsigned short*)ws; ws += DD * 2;
  unsigned short* Wob = (unsigned short*)ws; ws += DD * 2;
  unsigned short* Qp  = (unsigned short*)ws; ws += M * D_MODEL * 2;
  unsigned short* Kp  = (unsigned short*)ws; ws += M * D_MODEL * 2;
  unsigned short* Vp  = (unsigned short*)ws; ws += M * D_MODEL * 2;
  unsigned short* Ob  = (unsigned short*)ws; ws += M * D_MODEL * 2;

  // casts
  int n4x = (int)(M * D_MODEL / 4);
  cast_kernel<<<(n4x + 255) / 256, 256, 0, stream>>>(x, xb, n4x);
  cast4_kernel<<<4096, 256, 0, stream>>>(Wq, Wk, Wv, Wo, Wqb, Wkb, Wvb, Wob);

  // fused QKV projection
  gemm_bt<128, false><<<dim3(24, (unsigned)(M / 128)), 256, 0, stream>>>(
      xb, Wqb, Wkb, Wvb, Qp, Kp, Vp, (int)M, D_MODEL);

  // rope on Q,K in place (Q pre-scaled by (1/8)*log2e)
  int total = (int)(M * 512);
  rope_kernel<<<(total + 255) / 256, 256, 0, stream>>>(Qp, Kp, pos, total);

  // attention: paired q-tiles, XCD-grouped heads (512 uniform blocks, 1D)
  attn_kernel<<<dim3(512), 256, 0, stream>>>(Qp, Kp, Vp, Ob);

  // output projection (fp32 out)
  gemm_bt<64, true><<<dim3(16, (unsigned)(M / 128)), 256, 0, stream>>>(
      Ob, Wob, Wob, Wob, d_out, d_out, d_out, (int)M, D_MODEL);
}